// Round 6
// baseline (542.787 us; speedup 1.0000x reference)
//
#include <hip/hip_runtime.h>

#define N_NODES 50000
#define N_EDGES 800000
#define IN_DIM  162
#define HID     256
#define KPAD1   192   // IN_DIM padded to multiple of 32
#define NB      ((N_NODES + 255) / 256)   // 196 scan blocks

typedef __bf16 bf16;
typedef __bf16 bf16x8 __attribute__((ext_vector_type(8)));
typedef __bf16 bf16x4 __attribute__((ext_vector_type(4)));
typedef float  f32x4  __attribute__((ext_vector_type(4)));
typedef float  f32x8  __attribute__((ext_vector_type(8)));
typedef float  f32x16 __attribute__((ext_vector_type(16)));

// ---------------------------------------------------------------------------
// Frag-major weight pack: Wf element E holds the MFMA B-frag element
//   fb = j*2+kk, E = ((ks*16 + fb)*64 + lane)*8 + e
//   -> W[k][n], n = j*32 + (lane&31), k = ks*32 + kk*16 + (lane>>5)*8 + e
// This replicates exactly the LDS image the old global_load_lds staging
// produced (verified by prior passing rounds), so a wave's b-frag load is
// one contiguous 1KB coalesced read: Wf + ((ks*16+fb)*64 + lane)*8.
__device__ __forceinline__ void wf_one(const float* W, bf16* Wf, int K, int E)
{
    int e    = E & 7;
    int lane = (E >> 3) & 63;
    int fb   = (E >> 9) & 15;
    int ks   = E >> 13;
    int n = (fb >> 1) * 32 + (lane & 31);
    int k = ks * 32 + (fb & 1) * 16 + (lane >> 5) * 8 + e;
    Wf[E] = (k < K) ? (bf16)W[(size_t)k * HID + n] : (bf16)0.0f;
}

__global__ void wt_fragmajor_all(const float* __restrict__ m1aw, const float* __restrict__ m1bw,
                                 const float* __restrict__ m2aw, const float* __restrict__ m2bw,
                                 bf16* __restrict__ Wf1, bf16* __restrict__ Wf2,
                                 bf16* __restrict__ Wf3, bf16* __restrict__ Wf4)
{
    const int R1 = HID * KPAD1;
    const int R2 = HID * HID;
    int idx = blockIdx.x * blockDim.x + threadIdx.x;
    if (idx < R1)                 wf_one(m1aw, Wf1, IN_DIM, idx);
    else if (idx < R1 + R2)       wf_one(m1bw, Wf2, HID, idx - R1);
    else if (idx < R1 + 2 * R2)   wf_one(m2aw, Wf3, HID, idx - R1 - R2);
    else if (idx < R1 + 3 * R2)   wf_one(m2bw, Wf4, HID, idx - R1 - 2 * R2);
}

// ---------------------------------------------------------------------------
// feat f32 [N, IN_DIM] -> featbf bf16 TILED [8][N][24] (cols >= IN_DIM zeroed).
__global__ void feat_to_bf16(const float* __restrict__ feat, bf16* __restrict__ featbf)
{
    int idx = blockIdx.x * blockDim.x + threadIdx.x;  // over N*KPAD1/4
    int r = idx / (KPAD1 / 4);
    int c4 = (idx - r * (KPAD1 / 4)) * 4;
    if (r >= N_NODES) return;
    bf16x4 o;
#pragma unroll
    for (int j = 0; j < 4; ++j) {
        int c = c4 + j;
        o[j] = (c < IN_DIM) ? (bf16)feat[(size_t)r * IN_DIM + c] : (bf16)0.0f;
    }
    int gch = c4 / 24;
    int off = c4 - gch * 24;
    *(bf16x4*)(featbf + ((size_t)gch * N_NODES + r) * 24 + off) = o;
}

// ---------------------------------------------------------------------------
// colsum8[b&7][c] += partial column sums of feat (reads original f32 feat).
__global__ void colsum_feat8(const float* __restrict__ feat, float* __restrict__ colsum8)
{
    int c  = threadIdx.x;
    int r0 = blockIdx.x * 50;
    if (c >= IN_DIM) return;
    float acc = 0.0f;
#pragma unroll 2
    for (int i = 0; i < 50; ++i) {
        int r = r0 + i;
        if (r < N_NODES) acc += feat[(size_t)r * IN_DIM + c];
    }
    atomicAdd(&colsum8[(blockIdx.x & 7) * KPAD1 + c], acc);
}

// ---------------------------------------------------------------------------
// CSR build.
__global__ void degree_hist(const int* __restrict__ dst, int* __restrict__ deg)
{
    int e = blockIdx.x * blockDim.x + threadIdx.x;
    atomicAdd(&deg[dst[e]], 1);
}

__global__ void block_degsum(const int* __restrict__ deg, int* __restrict__ bsum)
{
    __shared__ int s[256];
    int t = threadIdx.x;
    int idx = blockIdx.x * 256 + t;
    int v = (idx < N_NODES) ? deg[idx] : 0;
    s[t] = v;
    __syncthreads();
    for (int off = 128; off > 0; off >>= 1) {
        if (t < off) s[t] += s[t + off];
        __syncthreads();
    }
    if (t == 0) bsum[blockIdx.x] = s[0];
}

__global__ void scan_bsum(const int* __restrict__ bsum, int* __restrict__ gsum)
{
    __shared__ int s[256];
    int t = threadIdx.x;
    int v = (t < NB) ? bsum[t] : 0;
    s[t] = v;
    __syncthreads();
    for (int off = 1; off < 256; off <<= 1) {
        int u = (t >= off) ? s[t - off] : 0;
        __syncthreads();
        s[t] += u;
        __syncthreads();
    }
    gsum[t] = s[t] - v;
}

__global__ void block_scan_write(const int* __restrict__ deg, const int* __restrict__ gsum,
                                 int* __restrict__ rowptr, int* __restrict__ cursor)
{
    __shared__ int s[256];
    int t = threadIdx.x;
    int idx = blockIdx.x * 256 + t;
    int v = (idx < N_NODES) ? deg[idx] : 0;
    s[t] = v;
    __syncthreads();
    for (int off = 1; off < 256; off <<= 1) {
        int u = (t >= off) ? s[t - off] : 0;
        __syncthreads();
        s[t] += u;
        __syncthreads();
    }
    int excl = s[t] - v + gsum[blockIdx.x];
    if (idx < N_NODES) {
        rowptr[idx] = excl;
        cursor[idx] = excl;
    }
    if (idx == 0) rowptr[N_NODES] = N_EDGES;
}

__global__ void csr_fill(const int* __restrict__ src, const int* __restrict__ dst,
                         int* __restrict__ cursor, int* __restrict__ csr_src)
{
    int e = blockIdx.x * blockDim.x + threadIdx.x;
    int p = atomicAdd(&cursor[dst[e]], 1);
    csr_src[p] = src[e];
}

// ---------------------------------------------------------------------------
// Gather v5: tiled [8][N][CHUNK] input/output, XCD-pinned groups, in-register
// index list, masked unrolled row-load blocks.
template<int CHUNK, int NACT>
__launch_bounds__(256)
__global__ void gather_v5(const bf16* __restrict__ xin,
                          const int* __restrict__ rowptr,
                          const int* __restrict__ csr_src,
                          bf16* __restrict__ xout)
{
    const int g    = blockIdx.x & 7;
    const int tile = blockIdx.x >> 3;
    const int wv   = threadIdx.x >> 6;
    const int lane = threadIdx.x & 63;
    const int q    = lane >> 4;          // node within wave 0..3
    const int j    = lane & 15;          // idx slot
    const int e    = j >> 2;             // stripe 0..3
    const int c4   = j & 3;              // 16B chunk
    const int n    = tile * 16 + wv * 4 + q;
    const bool valid = (n < N_NODES);
    const bool act   = (c4 < NACT);
    const int  ce    = c4 * 8;
    const bf16* base = xin + (size_t)g * N_NODES * CHUNK;

    int r0 = 0, deg = 0;
    if (valid) {
        r0  = rowptr[n];
        deg = rowptr[n + 1] - r0;
    }

    int a0 = r0 + j;        if (a0 > N_EDGES - 1) a0 = N_EDGES - 1;
    int a1 = r0 + 16 + j;   if (a1 > N_EDGES - 1) a1 = N_EDGES - 1;
    const int i0 = csr_src[a0];
    const int i1 = csr_src[a1];

    f32x8 acc;
#pragma unroll
    for (int t = 0; t < 8; ++t) acc[t] = 0.0f;
    if (valid && e == 0 && act) {
        bf16x8 t0 = *(const bf16x8*)(base + (size_t)n * CHUNK + ce);
#pragma unroll
        for (int t = 0; t < 8; ++t) acc[t] = (float)t0[t];
    }

    const int lb = lane & ~3;

    // ---- block 1: positions 4e + k ----
    {
        const int s0 = __shfl(i0, lb + 0, 64);
        const int s1 = __shfl(i0, lb + 1, 64);
        const int s2 = __shfl(i0, lb + 2, 64);
        const int s3 = __shfl(i0, lb + 3, 64);
        const int p0 = 4 * e;
        if (act) {
            bf16x8 u0 = *(const bf16x8*)(base + (size_t)s0 * CHUNK + ce);
            bf16x8 u1 = *(const bf16x8*)(base + (size_t)s1 * CHUNK + ce);
            bf16x8 u2 = *(const bf16x8*)(base + (size_t)s2 * CHUNK + ce);
            bf16x8 u3 = *(const bf16x8*)(base + (size_t)s3 * CHUNK + ce);
            if (p0 + 0 < deg) {
#pragma unroll
                for (int t = 0; t < 8; ++t) acc[t] += (float)u0[t];
            }
            if (p0 + 1 < deg) {
#pragma unroll
                for (int t = 0; t < 8; ++t) acc[t] += (float)u1[t];
            }
            if (p0 + 2 < deg) {
#pragma unroll
                for (int t = 0; t < 8; ++t) acc[t] += (float)u2[t];
            }
            if (p0 + 3 < deg) {
#pragma unroll
                for (int t = 0; t < 8; ++t) acc[t] += (float)u3[t];
            }
        }
    }

    // ---- block 2: positions 16 + 4e + k, stripe-gated ----
    {
        const int s0 = __shfl(i1, lb + 0, 64);
        const int s1 = __shfl(i1, lb + 1, 64);
        const int s2 = __shfl(i1, lb + 2, 64);
        const int s3 = __shfl(i1, lb + 3, 64);
        const int p0 = 16 + 4 * e;
        if (act && p0 < deg) {
            bf16x8 u0 = *(const bf16x8*)(base + (size_t)s0 * CHUNK + ce);
            bf16x8 u1 = *(const bf16x8*)(base + (size_t)s1 * CHUNK + ce);
            bf16x8 u2 = *(const bf16x8*)(base + (size_t)s2 * CHUNK + ce);
            bf16x8 u3 = *(const bf16x8*)(base + (size_t)s3 * CHUNK + ce);
            {
#pragma unroll
                for (int t = 0; t < 8; ++t) acc[t] += (float)u0[t];
            }
            if (p0 + 1 < deg) {
#pragma unroll
                for (int t = 0; t < 8; ++t) acc[t] += (float)u1[t];
            }
            if (p0 + 2 < deg) {
#pragma unroll
                for (int t = 0; t < 8; ++t) acc[t] += (float)u2[t];
            }
            if (p0 + 3 < deg) {
#pragma unroll
                for (int t = 0; t < 8; ++t) acc[t] += (float)u3[t];
            }
        }
    }

    // ---- rare tail: deg > 32 ----
    for (int p = 32 + e; p < deg; p += 4) {
        const int s = csr_src[r0 + p];
        if (act) {
            bf16x8 u = *(const bf16x8*)(base + (size_t)s * CHUNK + ce);
#pragma unroll
            for (int t = 0; t < 8; ++t) acc[t] += (float)u[t];
        }
    }

#pragma unroll
    for (int t = 0; t < 8; ++t) {
        acc[t] += __shfl_xor(acc[t], 4, 64);
        acc[t] += __shfl_xor(acc[t], 8, 64);
    }

    if (valid && e == 0 && act) {
        bf16x8 o;
#pragma unroll
        for (int t = 0; t < 8; ++t) o[t] = (bf16)acc[t];
        __builtin_nontemporal_store(o,
            (bf16x8*)(xout + ((size_t)g * N_NODES + n) * CHUNK + ce));
    }
}

// ---------------------------------------------------------------------------
// Fused GIN MLP: out = relu(relu(X@W1+b1)@W2+b2), colsum of out fused.
// Block = 4 waves, 128 rows; wave w owns rows [w*32, w*32+32).
// Phase 1: B-frags read coalesced from frag-major Wf1 (L2-resident), A from
// global; NO barriers in the K-loop. H = relu(.) written to XOR-swizzled LDS.
// Handoff is wave-local (wave w's phase-2 A-rows are the rows it computed),
// one __syncthreads for safety. Phase 2: A from LDS, B from Wf2; no barriers.
// ACHUNK: 0 = X linear [M][KPAD]; else X tiled [KPAD/ACHUNK][N_NODES][ACHUNK].
// OCHUNK: 0 = out linear [M][HID]; else out tiled [HID/32][N_NODES][32].
template<int KPAD, int ACHUNK, int OCHUNK>
__launch_bounds__(256)
__global__ void gemm_mlp(const bf16* __restrict__ X,
                         const bf16* __restrict__ Wf1,
                         const float* __restrict__ bias1,
                         const bf16* __restrict__ Wf2,
                         const float* __restrict__ bias2,
                         bf16* __restrict__ out_bf,
                         float* __restrict__ colsum,   // nullable
                         int M)
{
    __shared__ __align__(128) bf16 sH[128 * HID];   // 64 KB
    __shared__ float cs[HID];

    const int tid  = threadIdx.x;
    const int w    = tid >> 6;
    const int lane = tid & 63;
    const int p    = lane >> 5;
    const int cn   = lane & 31;
    const int m_base = blockIdx.x * 128 + w * 32;

    int arow = m_base + cn;
    if (arow >= M) arow = M - 1;   // clamp (stores guarded)

    f32x16 acc[8];
#pragma unroll
    for (int j = 0; j < 8; ++j)
#pragma unroll
        for (int r = 0; r < 16; ++r) acc[j][r] = 0.0f;

    // ---- phase 1: acc = X @ W1 (barrier-free) ----
#pragma unroll
    for (int ks = 0; ks < KPAD / 32; ++ks) {
#pragma unroll
        for (int kk = 0; kk < 2; ++kk) {
            bf16x8 a;
            if constexpr (ACHUNK == 0) {
                a = *(const bf16x8*)(X + (size_t)arow * KPAD + ks * 32 + kk * 16 + p * 8);
            } else {
                const int e   = ks * 32 + kk * 16 + p * 8;
                const int gch = e / ACHUNK;
                const int off = e - gch * ACHUNK;
                a = *(const bf16x8*)(X + ((size_t)gch * N_NODES + arow) * ACHUNK + off);
            }
#pragma unroll
            for (int j = 0; j < 8; ++j) {
                bf16x8 b = *(const bf16x8*)(Wf1 + (((ks * 16 + j * 2 + kk) * 64) + lane) * 8);
                acc[j] = __builtin_amdgcn_mfma_f32_32x32x16_bf16(a, b, acc[j], 0, 0, 0);
            }
        }
    }

    // ---- epilogue 1: H = relu(acc + b1) -> LDS (row-XOR swizzle) ----
    char* sHb = (char*)sH;
#pragma unroll
    for (int j = 0; j < 8; ++j) {
        const float bv = bias1[j * 32 + cn];
#pragma unroll
        for (int r = 0; r < 16; ++r) {
            const int rowl = (r & 3) + 8 * (r >> 2) + 4 * p;
            const int rowf = w * 32 + rowl;
            float v = acc[j][r] + bv;
            v = v > 0.0f ? v : 0.0f;
            int ba = rowf * (HID * 2) + (j * 32 + cn) * 2;
            ba ^= (rowf & 7) << 4;
            *(bf16*)(sHb + ba) = (bf16)v;
        }
    }
    __syncthreads();

    // ---- phase 2: acc = H @ W2 (A from LDS, barrier-free) ----
#pragma unroll
    for (int j = 0; j < 8; ++j)
#pragma unroll
        for (int r = 0; r < 16; ++r) acc[j][r] = 0.0f;

    const int hrow = w * 32 + cn;
    const int hswz = (hrow & 7) << 4;
#pragma unroll
    for (int ks = 0; ks < HID / 32; ++ks) {
#pragma unroll
        for (int kk = 0; kk < 2; ++kk) {
            const int kb = (ks * 32 + kk * 16 + p * 8) * 2;
            bf16x8 a = *(const bf16x8*)(sHb + ((hrow * (HID * 2) + kb) ^ hswz));
#pragma unroll
            for (int j = 0; j < 8; ++j) {
                bf16x8 b = *(const bf16x8*)(Wf2 + (((ks * 16 + j * 2 + kk) * 64) + lane) * 8);
                acc[j] = __builtin_amdgcn_mfma_f32_32x32x16_bf16(a, b, acc[j], 0, 0, 0);
            }
        }
    }

    // ---- epilogue 2: bias2 + relu + store + colsum ----
    if (colsum) {
        cs[tid] = 0.0f;
        __syncthreads();
    }

#pragma unroll
    for (int j = 0; j < 8; ++j) {
        const int col = j * 32 + cn;
        const float bv = bias2[col];
        float part = 0.0f;
#pragma unroll
        for (int r = 0; r < 16; ++r) {
            int rl = (r & 3) + 8 * (r >> 2) + 4 * p;
            int mo = m_base + rl;
            if (mo < M) {
                float v = acc[j][r] + bv;
                v = v > 0.0f ? v : 0.0f;
                if constexpr (OCHUNK == 0)
                    out_bf[(size_t)mo * HID + col] = (bf16)v;
                else
                    out_bf[((size_t)j * N_NODES + mo) * OCHUNK + cn] = (bf16)v;
                part += v;
            }
        }
        if (colsum) {
            part += __shfl_xor(part, 32, 64);   // combine the two p-halves
            if (p == 0) atomicAdd(&cs[col], part);
        }
    }

    if (colsum) {
        __syncthreads();
        atomicAdd(&colsum[tid], cs[tid]);
    }
}

// ---------------------------------------------------------------------------
// Graph head: three GEMVs + sum + final GEMV, single block of 256 threads.
__global__ void graph_head(const float* __restrict__ cs0_8,
                           const float* __restrict__ cs1,
                           const float* __restrict__ cs2,
                           const float* __restrict__ g0w, const float* __restrict__ g0b,
                           const float* __restrict__ g1w, const float* __restrict__ g1b,
                           const float* __restrict__ g2w, const float* __restrict__ g2b,
                           const float* __restrict__ glw, const float* __restrict__ glb,
                           float* __restrict__ gvec)
{
    __shared__ float v0[IN_DIM], v1[HID], v2[HID], gs[HID];
    int t = threadIdx.x;
    if (t < IN_DIM) {
        float s = 0.0f;
#pragma unroll
        for (int i = 0; i < 8; ++i) s += cs0_8[i * KPAD1 + t];
        v0[t] = s;
    }
    v1[t] = cs1[t];
    v2[t] = cs2[t];
    __syncthreads();

    float a0 = 0.0f, a1 = 0.0f, a2 = 0.0f;
    for (int k = 0; k < IN_DIM; ++k) a0 += v0[k] * g0w[k * HID + t];
    for (int k = 0; k < HID; ++k) {
        a1 += v1[k] * g1w[k * HID + t];
        a2 += v2[k] * g2w[k * HID + t];
    }
    float e0 = fmaxf(a0 + g0b[t], 0.0f);
    float e1 = fmaxf(a1 + g1b[t], 0.0f);
    float e2 = fmaxf(a2 + g2b[t], 0.0f);
    gs[t] = e0 + e1 + e2;
    __syncthreads();

    float a3 = 0.0f;
    for (int k = 0; k < HID; ++k) a3 += gs[k] * glw[k * HID + t];
    gvec[t] = fmaxf(a3 + glb[t], 0.0f);
}

// ---------------------------------------------------------------------------
// out[n,c] = node2[n,c](bf16) + gvec[c] (f32 out); 4 elements per thread.
__global__ void final_add(const bf16* __restrict__ node2,
                          const float* __restrict__ gvec,
                          float* __restrict__ out)
{
    int idx = blockIdx.x * blockDim.x + threadIdx.x;
    size_t base = (size_t)idx * 4;
    int c = (int)(base & (HID - 1));
    bf16x4 v = *(const bf16x4*)(node2 + base);
    f32x4 g = *(const f32x4*)(gvec + c);
    f32x4 o;
#pragma unroll
    for (int j = 0; j < 4; ++j) o[j] = (float)v[j] + g[j];
    *(f32x4*)(out + base) = o;
}

// ---------------------------------------------------------------------------
extern "C" void kernel_launch(void* const* d_in, const int* in_sizes, int n_in,
                              void* d_out, int out_size, void* d_ws, size_t ws_size,
                              hipStream_t stream)
{
    const float* feat = (const float*)d_in[0];
    const int*   ei   = (const int*)d_in[1];
    const int*   src  = ei;
    const int*   dst  = ei + N_EDGES;
    const float* g0w = (const float*)d_in[2],  *g0b = (const float*)d_in[3];
    const float* g1w = (const float*)d_in[4],  *g1b = (const float*)d_in[5];
    const float* g2w = (const float*)d_in[6],  *g2b = (const float*)d_in[7];
    const float* glw = (const float*)d_in[8],  *glb = (const float*)d_in[9];
    const float* m1aw = (const float*)d_in[10], *m1ab = (const float*)d_in[11];
    const float* m1bw = (const float*)d_in[12], *m1bb = (const float*)d_in[13];
    const float* m2aw = (const float*)d_in[14], *m2ab = (const float*)d_in[15];
    const float* m2bw = (const float*)d_in[16], *m2bb = (const float*)d_in[17];
    float* out = (float*)d_out;

    char* ws = (char*)d_ws;
    size_t off = 0;
    auto alloc = [&](size_t bytes) -> void* {
        void* p = ws + off;
        off += (bytes + 255) & ~(size_t)255;
        return p;
    };
    bf16*  featbf = (bf16*)alloc((size_t)N_NODES * KPAD1 * 2);   // tiled [8][N][24]
    bf16*  xsum  = (bf16*) alloc((size_t)N_NODES * KPAD1 * 2);   // tiled [8][N][24]
    bf16*  y2    = (bf16*) alloc((size_t)N_NODES * HID * 2);     // tiled [8][N][32]
    bf16*  node2 = (bf16*) alloc((size_t)N_NODES * HID * 2);     // linear
    bf16*  node1 = (bf16*) alloc((size_t)N_NODES * HID * 2);     // tiled [8][N][32]
    bf16*  Wf1   = (bf16*) alloc((size_t)HID * KPAD1 * 2);       // frag-major
    bf16*  Wf2   = (bf16*) alloc((size_t)HID * HID * 2);
    bf16*  Wf3   = (bf16*) alloc((size_t)HID * HID * 2);
    bf16*  Wf4   = (bf16*) alloc((size_t)HID * HID * 2);
    int*   deg     = (int*)alloc((size_t)N_NODES * 4);
    int*   rowptr  = (int*)alloc((size_t)(N_NODES + 1) * 4);
    int*   cursor  = (int*)alloc((size_t)N_NODES * 4);
    int*   csr_src = (int*)alloc((size_t)N_EDGES * 4);
    int*   bsum    = (int*)alloc(256 * 4);
    int*   gsum    = (int*)alloc(256 * 4);
    float* csums   = (float*)alloc((8 * KPAD1 + 256 + 256 + 256) * 4);
    float* colsum0_8 = csums;                    // 8 x 192 partial slots
    float* colsum1   = csums + 8 * KPAD1;        // 256
    float* colsum2   = csums + 8 * KPAD1 + 256;  // 256
    float* gvec      = csums + 8 * KPAD1 + 512;  // 256

    hipMemsetAsync(csums, 0, (8 * KPAD1 + 512) * 4, stream);
    hipMemsetAsync(deg, 0, (size_t)N_NODES * 4, stream);

    // all 4 weight packs (frag-major), one launch
    wt_fragmajor_all<<<(HID * KPAD1 + 3 * HID * HID + 255) / 256, 256, 0, stream>>>(
        m1aw, m1bw, m2aw, m2bw, Wf1, Wf2, Wf3, Wf4);

    // feat -> bf16 tiled
    feat_to_bf16<<<((size_t)N_NODES * (KPAD1 / 4) + 255) / 256, 256, 0, stream>>>(feat, featbf);
    // colsum0 partials (8-slot spread)
    colsum_feat8<<<1000, 192, 0, stream>>>(feat, colsum0_8);

    // CSR build (grouped by dst)
    degree_hist<<<N_EDGES / 256, 256, 0, stream>>>(dst, deg);
    block_degsum<<<NB, 256, 0, stream>>>(deg, bsum);
    scan_bsum<<<1, 256, 0, stream>>>(bsum, gsum);
    block_scan_write<<<NB, 256, 0, stream>>>(deg, gsum, rowptr, cursor);
    csr_fill<<<N_EDGES / 256, 256, 0, stream>>>(src, dst, cursor, csr_src);

    const int gtiles = (N_NODES + 15) / 16;   // 4 nodes/wave x 4 waves
    // xsum = bf16(feat + gather(feat)) — tiled, XCD-pinned, register-idx
    gather_v5<24, 3><<<gtiles * 8, 256, 0, stream>>>(featbf, rowptr, csr_src, xsum);

    const int gblocks = (N_NODES + 127) / 128;
    // node1 = relu(relu(xsum@W1+b1)@W2+b2), colsum1 fused   (A tiled24 -> tiled32 out)
    gemm_mlp<KPAD1, 24, 32><<<gblocks, 256, 0, stream>>>(
        xsum, Wf1, m1ab, Wf2, m1bb, node1, colsum1, N_NODES);
    // y2 = bf16(node1 + gather(node1)) — tiled, XCD-pinned, register-idx
    gather_v5<32, 4><<<gtiles * 8, 256, 0, stream>>>(node1, rowptr, csr_src, y2);
    // node2 = relu(relu(y2@W3+b3)@W4+b4), colsum2 fused     (A tiled32 -> linear out)
    gemm_mlp<HID, 32, 0><<<gblocks, 256, 0, stream>>>(
        y2, Wf3, m2ab, Wf4, m2bb, node2, colsum2, N_NODES);
    // graph head -> gvec = g_last
    graph_head<<<1, 256, 0, stream>>>(colsum0_8, colsum1, colsum2,
                                      g0w, g0b, g1w, g1b, g2w, g2b, glw, glb, gvec);
    // out = node2 + gvec
    final_add<<<((size_t)N_NODES * HID / 4 + 255) / 256, 256, 0, stream>>>(node2, gvec, out);
    (void)in_sizes; (void)n_in; (void)out_size; (void)ws_size;
}

// Round 7
// 468.349 us; speedup vs baseline: 1.1589x; 1.1589x over previous
//
#include <hip/hip_runtime.h>

#define N_NODES 50000
#define N_EDGES 800000
#define IN_DIM  162
#define HID     256
#define KPAD1   192   // IN_DIM padded to multiple of 32
#define NB      ((N_NODES + 255) / 256)   // 196 scan blocks

typedef __bf16 bf16;
typedef __bf16 bf16x8 __attribute__((ext_vector_type(8)));
typedef __bf16 bf16x4 __attribute__((ext_vector_type(4)));
typedef float  f32x4  __attribute__((ext_vector_type(4)));
typedef float  f32x8  __attribute__((ext_vector_type(8)));
typedef float  f32x16 __attribute__((ext_vector_type(16)));

// ---------------------------------------------------------------------------
// Frag-major weight pack: Wf element E holds the MFMA B-frag element
//   fb = jg*2+kk, E = ((ks*16 + fb)*64 + lane)*8 + e
//   -> W[k][n], n = jg*32 + (lane&31), k = ks*32 + kk*16 + (lane>>5)*8 + e
// A wave's b-frag load is one contiguous 1KB coalesced read.
__device__ __forceinline__ void wf_one(const float* W, bf16* Wf, int K, int E)
{
    int e    = E & 7;
    int lane = (E >> 3) & 63;
    int fb   = (E >> 9) & 15;
    int ks   = E >> 13;
    int n = (fb >> 1) * 32 + (lane & 31);
    int k = ks * 32 + (fb & 1) * 16 + (lane >> 5) * 8 + e;
    Wf[E] = (k < K) ? (bf16)W[(size_t)k * HID + n] : (bf16)0.0f;
}

__global__ void wt_fragmajor_all(const float* __restrict__ m1aw, const float* __restrict__ m1bw,
                                 const float* __restrict__ m2aw, const float* __restrict__ m2bw,
                                 bf16* __restrict__ Wf1, bf16* __restrict__ Wf2,
                                 bf16* __restrict__ Wf3, bf16* __restrict__ Wf4)
{
    const int R1 = HID * KPAD1;
    const int R2 = HID * HID;
    int idx = blockIdx.x * blockDim.x + threadIdx.x;
    if (idx < R1)                 wf_one(m1aw, Wf1, IN_DIM, idx);
    else if (idx < R1 + R2)       wf_one(m1bw, Wf2, HID, idx - R1);
    else if (idx < R1 + 2 * R2)   wf_one(m2aw, Wf3, HID, idx - R1 - R2);
    else if (idx < R1 + 3 * R2)   wf_one(m2bw, Wf4, HID, idx - R1 - 2 * R2);
}

// ---------------------------------------------------------------------------
// feat f32 [N, IN_DIM] -> featbf bf16 TILED [8][N][24] (cols >= IN_DIM zeroed).
__global__ void feat_to_bf16(const float* __restrict__ feat, bf16* __restrict__ featbf)
{
    int idx = blockIdx.x * blockDim.x + threadIdx.x;  // over N*KPAD1/4
    int r = idx / (KPAD1 / 4);
    int c4 = (idx - r * (KPAD1 / 4)) * 4;
    if (r >= N_NODES) return;
    bf16x4 o;
#pragma unroll
    for (int j = 0; j < 4; ++j) {
        int c = c4 + j;
        o[j] = (c < IN_DIM) ? (bf16)feat[(size_t)r * IN_DIM + c] : (bf16)0.0f;
    }
    int gch = c4 / 24;
    int off = c4 - gch * 24;
    *(bf16x4*)(featbf + ((size_t)gch * N_NODES + r) * 24 + off) = o;
}

// ---------------------------------------------------------------------------
// colsum8[b&7][c] += partial column sums of feat (reads original f32 feat).
__global__ void colsum_feat8(const float* __restrict__ feat, float* __restrict__ colsum8)
{
    int c  = threadIdx.x;
    int r0 = blockIdx.x * 50;
    if (c >= IN_DIM) return;
    float acc = 0.0f;
#pragma unroll 2
    for (int i = 0; i < 50; ++i) {
        int r = r0 + i;
        if (r < N_NODES) acc += feat[(size_t)r * IN_DIM + c];
    }
    atomicAdd(&colsum8[(blockIdx.x & 7) * KPAD1 + c], acc);
}

// ---------------------------------------------------------------------------
// CSR build.
__global__ void degree_hist(const int* __restrict__ dst, int* __restrict__ deg)
{
    int e = blockIdx.x * blockDim.x + threadIdx.x;
    atomicAdd(&deg[dst[e]], 1);
}

__global__ void block_degsum(const int* __restrict__ deg, int* __restrict__ bsum)
{
    __shared__ int s[256];
    int t = threadIdx.x;
    int idx = blockIdx.x * 256 + t;
    int v = (idx < N_NODES) ? deg[idx] : 0;
    s[t] = v;
    __syncthreads();
    for (int off = 128; off > 0; off >>= 1) {
        if (t < off) s[t] += s[t + off];
        __syncthreads();
    }
    if (t == 0) bsum[blockIdx.x] = s[0];
}

__global__ void scan_bsum(const int* __restrict__ bsum, int* __restrict__ gsum)
{
    __shared__ int s[256];
    int t = threadIdx.x;
    int v = (t < NB) ? bsum[t] : 0;
    s[t] = v;
    __syncthreads();
    for (int off = 1; off < 256; off <<= 1) {
        int u = (t >= off) ? s[t - off] : 0;
        __syncthreads();
        s[t] += u;
        __syncthreads();
    }
    gsum[t] = s[t] - v;
}

__global__ void block_scan_write(const int* __restrict__ deg, const int* __restrict__ gsum,
                                 int* __restrict__ rowptr, int* __restrict__ cursor)
{
    __shared__ int s[256];
    int t = threadIdx.x;
    int idx = blockIdx.x * 256 + t;
    int v = (idx < N_NODES) ? deg[idx] : 0;
    s[t] = v;
    __syncthreads();
    for (int off = 1; off < 256; off <<= 1) {
        int u = (t >= off) ? s[t - off] : 0;
        __syncthreads();
        s[t] += u;
        __syncthreads();
    }
    int excl = s[t] - v + gsum[blockIdx.x];
    if (idx < N_NODES) {
        rowptr[idx] = excl;
        cursor[idx] = excl;
    }
    if (idx == 0) rowptr[N_NODES] = N_EDGES;
}

__global__ void csr_fill(const int* __restrict__ src, const int* __restrict__ dst,
                         int* __restrict__ cursor, int* __restrict__ csr_src)
{
    int e = blockIdx.x * blockDim.x + threadIdx.x;
    int p = atomicAdd(&cursor[dst[e]], 1);
    csr_src[p] = src[e];
}

// ---------------------------------------------------------------------------
// Gather v5: tiled [8][N][CHUNK] input/output, XCD-pinned groups, in-register
// index list, masked unrolled row-load blocks.
template<int CHUNK, int NACT>
__launch_bounds__(256)
__global__ void gather_v5(const bf16* __restrict__ xin,
                          const int* __restrict__ rowptr,
                          const int* __restrict__ csr_src,
                          bf16* __restrict__ xout)
{
    const int g    = blockIdx.x & 7;
    const int tile = blockIdx.x >> 3;
    const int wv   = threadIdx.x >> 6;
    const int lane = threadIdx.x & 63;
    const int q    = lane >> 4;          // node within wave 0..3
    const int j    = lane & 15;          // idx slot
    const int e    = j >> 2;             // stripe 0..3
    const int c4   = j & 3;              // 16B chunk
    const int n    = tile * 16 + wv * 4 + q;
    const bool valid = (n < N_NODES);
    const bool act   = (c4 < NACT);
    const int  ce    = c4 * 8;
    const bf16* base = xin + (size_t)g * N_NODES * CHUNK;

    int r0 = 0, deg = 0;
    if (valid) {
        r0  = rowptr[n];
        deg = rowptr[n + 1] - r0;
    }

    int a0 = r0 + j;        if (a0 > N_EDGES - 1) a0 = N_EDGES - 1;
    int a1 = r0 + 16 + j;   if (a1 > N_EDGES - 1) a1 = N_EDGES - 1;
    const int i0 = csr_src[a0];
    const int i1 = csr_src[a1];

    f32x8 acc;
#pragma unroll
    for (int t = 0; t < 8; ++t) acc[t] = 0.0f;
    if (valid && e == 0 && act) {
        bf16x8 t0 = *(const bf16x8*)(base + (size_t)n * CHUNK + ce);
#pragma unroll
        for (int t = 0; t < 8; ++t) acc[t] = (float)t0[t];
    }

    const int lb = lane & ~3;

    // ---- block 1: positions 4e + k ----
    {
        const int s0 = __shfl(i0, lb + 0, 64);
        const int s1 = __shfl(i0, lb + 1, 64);
        const int s2 = __shfl(i0, lb + 2, 64);
        const int s3 = __shfl(i0, lb + 3, 64);
        const int p0 = 4 * e;
        if (act) {
            bf16x8 u0 = *(const bf16x8*)(base + (size_t)s0 * CHUNK + ce);
            bf16x8 u1 = *(const bf16x8*)(base + (size_t)s1 * CHUNK + ce);
            bf16x8 u2 = *(const bf16x8*)(base + (size_t)s2 * CHUNK + ce);
            bf16x8 u3 = *(const bf16x8*)(base + (size_t)s3 * CHUNK + ce);
            if (p0 + 0 < deg) {
#pragma unroll
                for (int t = 0; t < 8; ++t) acc[t] += (float)u0[t];
            }
            if (p0 + 1 < deg) {
#pragma unroll
                for (int t = 0; t < 8; ++t) acc[t] += (float)u1[t];
            }
            if (p0 + 2 < deg) {
#pragma unroll
                for (int t = 0; t < 8; ++t) acc[t] += (float)u2[t];
            }
            if (p0 + 3 < deg) {
#pragma unroll
                for (int t = 0; t < 8; ++t) acc[t] += (float)u3[t];
            }
        }
    }

    // ---- block 2: positions 16 + 4e + k, stripe-gated ----
    {
        const int s0 = __shfl(i1, lb + 0, 64);
        const int s1 = __shfl(i1, lb + 1, 64);
        const int s2 = __shfl(i1, lb + 2, 64);
        const int s3 = __shfl(i1, lb + 3, 64);
        const int p0 = 16 + 4 * e;
        if (act && p0 < deg) {
            bf16x8 u0 = *(const bf16x8*)(base + (size_t)s0 * CHUNK + ce);
            bf16x8 u1 = *(const bf16x8*)(base + (size_t)s1 * CHUNK + ce);
            bf16x8 u2 = *(const bf16x8*)(base + (size_t)s2 * CHUNK + ce);
            bf16x8 u3 = *(const bf16x8*)(base + (size_t)s3 * CHUNK + ce);
            {
#pragma unroll
                for (int t = 0; t < 8; ++t) acc[t] += (float)u0[t];
            }
            if (p0 + 1 < deg) {
#pragma unroll
                for (int t = 0; t < 8; ++t) acc[t] += (float)u1[t];
            }
            if (p0 + 2 < deg) {
#pragma unroll
                for (int t = 0; t < 8; ++t) acc[t] += (float)u2[t];
            }
            if (p0 + 3 < deg) {
#pragma unroll
                for (int t = 0; t < 8; ++t) acc[t] += (float)u3[t];
            }
        }
    }

    // ---- rare tail: deg > 32 ----
    for (int p = 32 + e; p < deg; p += 4) {
        const int s = csr_src[r0 + p];
        if (act) {
            bf16x8 u = *(const bf16x8*)(base + (size_t)s * CHUNK + ce);
#pragma unroll
            for (int t = 0; t < 8; ++t) acc[t] += (float)u[t];
        }
    }

#pragma unroll
    for (int t = 0; t < 8; ++t) {
        acc[t] += __shfl_xor(acc[t], 4, 64);
        acc[t] += __shfl_xor(acc[t], 8, 64);
    }

    if (valid && e == 0 && act) {
        bf16x8 o;
#pragma unroll
        for (int t = 0; t < 8; ++t) o[t] = (bf16)acc[t];
        __builtin_nontemporal_store(o,
            (bf16x8*)(xout + ((size_t)g * N_NODES + n) * CHUNK + ce));
    }
}

// ---------------------------------------------------------------------------
// Fused GIN MLP v8: out = relu(relu(X@W1+b1)@W2+b2), colsum fused.
// 8 waves/block, 64 rows/block; wave w: rw = w&1 (row half), cw = w>>1
// (col quarter) -> per-wave tile 32 rows x 64 cols (acc = 2 x f32x16 = 32 VGPR).
// 782 blocks x 8 waves = 6256 waves (4x round-6) for latency hiding.
// B-frags coalesced from frag-major Wf (L2-resident); no K-loop barriers.
// H in LDS (32KB), full (row&31)<<4 XOR swizzle -> conflict-free phase-2 b128.
// ACHUNK: 0 = X linear [M][KPAD]; else X tiled [KPAD/ACHUNK][N_NODES][ACHUNK].
// OCHUNK: 0 = out linear [M][HID]; else out tiled [HID/32][N_NODES][32].
template<int KPAD, int ACHUNK, int OCHUNK>
__launch_bounds__(512)
__global__ void gemm_mlp8(const bf16* __restrict__ X,
                          const bf16* __restrict__ Wf1,
                          const float* __restrict__ bias1,
                          const bf16* __restrict__ Wf2,
                          const float* __restrict__ bias2,
                          bf16* __restrict__ out_bf,
                          float* __restrict__ colsum,   // nullable
                          int M)
{
    __shared__ __align__(128) bf16 sH[64 * HID];   // 32 KB
    __shared__ float cs[HID];

    const int tid  = threadIdx.x;
    const int w    = tid >> 6;
    const int lane = tid & 63;
    const int p    = lane >> 5;
    const int cn   = lane & 31;
    const int rw   = w & 1;        // row half 0/1
    const int cw   = w >> 1;       // col quarter 0..3
    const int m_base = blockIdx.x * 64;

    int arow = m_base + rw * 32 + cn;
    if (arow >= M) arow = M - 1;   // clamp (stores guarded)

    f32x16 accA, accB;             // jj = 0,1
#pragma unroll
    for (int r = 0; r < 16; ++r) { accA[r] = 0.0f; accB[r] = 0.0f; }

    // ---- phase 1: acc = X @ W1 (barrier-free) ----
#pragma unroll
    for (int ks = 0; ks < KPAD / 32; ++ks) {
#pragma unroll
        for (int kk = 0; kk < 2; ++kk) {
            bf16x8 a;
            if constexpr (ACHUNK == 0) {
                a = *(const bf16x8*)(X + (size_t)arow * KPAD + ks * 32 + kk * 16 + p * 8);
            } else {
                const int e   = ks * 32 + kk * 16 + p * 8;
                const int gch = e / ACHUNK;
                const int off = e - gch * ACHUNK;
                a = *(const bf16x8*)(X + ((size_t)gch * N_NODES + arow) * ACHUNK + off);
            }
            const int jg0 = cw * 2;
            bf16x8 b0 = *(const bf16x8*)(Wf1 + (((ks * 16 + (jg0 + 0) * 2 + kk) * 64) + lane) * 8);
            bf16x8 b1 = *(const bf16x8*)(Wf1 + (((ks * 16 + (jg0 + 1) * 2 + kk) * 64) + lane) * 8);
            accA = __builtin_amdgcn_mfma_f32_32x32x16_bf16(a, b0, accA, 0, 0, 0);
            accB = __builtin_amdgcn_mfma_f32_32x32x16_bf16(a, b1, accB, 0, 0, 0);
        }
    }

    // ---- epilogue 1: H = relu(acc + b1) -> LDS, (row&31)<<4 swizzle ----
    char* sHb = (char*)sH;
#pragma unroll
    for (int jj = 0; jj < 2; ++jj) {
        const int col = cw * 64 + jj * 32 + cn;
        const float bv = bias1[col];
#pragma unroll
        for (int r = 0; r < 16; ++r) {
            const int rowl = (r & 3) + 8 * (r >> 2) + 4 * p;
            const int rowf = rw * 32 + rowl;
            float v = (jj == 0 ? accA[r] : accB[r]) + bv;
            v = v > 0.0f ? v : 0.0f;
            int ba = rowf * (HID * 2) + col * 2;
            ba ^= (rowf & 31) << 4;
            *(bf16*)(sHb + ba) = (bf16)v;
        }
    }
    __syncthreads();

    // ---- phase 2: acc = H @ W2 (A from LDS, barrier-free) ----
#pragma unroll
    for (int r = 0; r < 16; ++r) { accA[r] = 0.0f; accB[r] = 0.0f; }

    const int hrow = rw * 32 + cn;
    const int hswz = (hrow & 31) << 4;
#pragma unroll
    for (int ks = 0; ks < HID / 32; ++ks) {
#pragma unroll
        for (int kk = 0; kk < 2; ++kk) {
            const int kb = (ks * 32 + kk * 16 + p * 8) * 2;
            bf16x8 a = *(const bf16x8*)(sHb + ((hrow * (HID * 2) + kb) ^ hswz));
            const int jg0 = cw * 2;
            bf16x8 b0 = *(const bf16x8*)(Wf2 + (((ks * 16 + (jg0 + 0) * 2 + kk) * 64) + lane) * 8);
            bf16x8 b1 = *(const bf16x8*)(Wf2 + (((ks * 16 + (jg0 + 1) * 2 + kk) * 64) + lane) * 8);
            accA = __builtin_amdgcn_mfma_f32_32x32x16_bf16(a, b0, accA, 0, 0, 0);
            accB = __builtin_amdgcn_mfma_f32_32x32x16_bf16(a, b1, accB, 0, 0, 0);
        }
    }

    // ---- epilogue 2: bias2 + relu + store + colsum ----
    if (colsum) {
        if (tid < HID) cs[tid] = 0.0f;
        __syncthreads();
    }

#pragma unroll
    for (int jj = 0; jj < 2; ++jj) {
        const int jg  = cw * 2 + jj;
        const int col = jg * 32 + cn;
        const float bv = bias2[col];
        float part = 0.0f;
#pragma unroll
        for (int r = 0; r < 16; ++r) {
            int rl = (r & 3) + 8 * (r >> 2) + 4 * p;
            int mo = m_base + rw * 32 + rl;
            if (mo < M) {
                float v = (jj == 0 ? accA[r] : accB[r]) + bv;
                v = v > 0.0f ? v : 0.0f;
                if constexpr (OCHUNK == 0)
                    out_bf[(size_t)mo * HID + col] = (bf16)v;
                else
                    out_bf[((size_t)jg * N_NODES + mo) * OCHUNK + cn] = (bf16)v;
                part += v;
            }
        }
        if (colsum) {
            part += __shfl_xor(part, 32, 64);   // combine the two p-halves
            if (p == 0) atomicAdd(&cs[col], part);
        }
    }

    if (colsum) {
        __syncthreads();
        if (tid < HID) atomicAdd(&colsum[tid], cs[tid]);
    }
}

// ---------------------------------------------------------------------------
// Graph head: three GEMVs + sum + final GEMV, single block of 256 threads.
__global__ void graph_head(const float* __restrict__ cs0_8,
                           const float* __restrict__ cs1,
                           const float* __restrict__ cs2,
                           const float* __restrict__ g0w, const float* __restrict__ g0b,
                           const float* __restrict__ g1w, const float* __restrict__ g1b,
                           const float* __restrict__ g2w, const float* __restrict__ g2b,
                           const float* __restrict__ glw, const float* __restrict__ glb,
                           float* __restrict__ gvec)
{
    __shared__ float v0[IN_DIM], v1[HID], v2[HID], gs[HID];
    int t = threadIdx.x;
    if (t < IN_DIM) {
        float s = 0.0f;
#pragma unroll
        for (int i = 0; i < 8; ++i) s += cs0_8[i * KPAD1 + t];
        v0[t] = s;
    }
    v1[t] = cs1[t];
    v2[t] = cs2[t];
    __syncthreads();

    float a0 = 0.0f, a1 = 0.0f, a2 = 0.0f;
    for (int k = 0; k < IN_DIM; ++k) a0 += v0[k] * g0w[k * HID + t];
    for (int k = 0; k < HID; ++k) {
        a1 += v1[k] * g1w[k * HID + t];
        a2 += v2[k] * g2w[k * HID + t];
    }
    float e0 = fmaxf(a0 + g0b[t], 0.0f);
    float e1 = fmaxf(a1 + g1b[t], 0.0f);
    float e2 = fmaxf(a2 + g2b[t], 0.0f);
    gs[t] = e0 + e1 + e2;
    __syncthreads();

    float a3 = 0.0f;
    for (int k = 0; k < HID; ++k) a3 += gs[k] * glw[k * HID + t];
    gvec[t] = fmaxf(a3 + glb[t], 0.0f);
}

// ---------------------------------------------------------------------------
// out[n,c] = node2[n,c](bf16) + gvec[c] (f32 out); 4 elements per thread.
__global__ void final_add(const bf16* __restrict__ node2,
                          const float* __restrict__ gvec,
                          float* __restrict__ out)
{
    int idx = blockIdx.x * blockDim.x + threadIdx.x;
    size_t base = (size_t)idx * 4;
    int c = (int)(base & (HID - 1));
    bf16x4 v = *(const bf16x4*)(node2 + base);
    f32x4 g = *(const f32x4*)(gvec + c);
    f32x4 o;
#pragma unroll
    for (int j = 0; j < 4; ++j) o[j] = (float)v[j] + g[j];
    *(f32x4*)(out + base) = o;
}

// ---------------------------------------------------------------------------
extern "C" void kernel_launch(void* const* d_in, const int* in_sizes, int n_in,
                              void* d_out, int out_size, void* d_ws, size_t ws_size,
                              hipStream_t stream)
{
    const float* feat = (const float*)d_in[0];
    const int*   ei   = (const int*)d_in[1];
    const int*   src  = ei;
    const int*   dst  = ei + N_EDGES;
    const float* g0w = (const float*)d_in[2],  *g0b = (const float*)d_in[3];
    const float* g1w = (const float*)d_in[4],  *g1b = (const float*)d_in[5];
    const float* g2w = (const float*)d_in[6],  *g2b = (const float*)d_in[7];
    const float* glw = (const float*)d_in[8],  *glb = (const float*)d_in[9];
    const float* m1aw = (const float*)d_in[10], *m1ab = (const float*)d_in[11];
    const float* m1bw = (const float*)d_in[12], *m1bb = (const float*)d_in[13];
    const float* m2aw = (const float*)d_in[14], *m2ab = (const float*)d_in[15];
    const float* m2bw = (const float*)d_in[16], *m2bb = (const float*)d_in[17];
    float* out = (float*)d_out;

    char* ws = (char*)d_ws;
    size_t off = 0;
    auto alloc = [&](size_t bytes) -> void* {
        void* p = ws + off;
        off += (bytes + 255) & ~(size_t)255;
        return p;
    };
    bf16*  featbf = (bf16*)alloc((size_t)N_NODES * KPAD1 * 2);   // tiled [8][N][24]
    bf16*  xsum  = (bf16*) alloc((size_t)N_NODES * KPAD1 * 2);   // tiled [8][N][24]
    bf16*  y2    = (bf16*) alloc((size_t)N_NODES * HID * 2);     // tiled [8][N][32]
    bf16*  node2 = (bf16*) alloc((size_t)N_NODES * HID * 2);     // linear
    bf16*  node1 = (bf16*) alloc((size_t)N_NODES * HID * 2);     // tiled [8][N][32]
    bf16*  Wf1   = (bf16*) alloc((size_t)HID * KPAD1 * 2);       // frag-major
    bf16*  Wf2   = (bf16*) alloc((size_t)HID * HID * 2);
    bf16*  Wf3   = (bf16*) alloc((size_t)HID * HID * 2);
    bf16*  Wf4   = (bf16*) alloc((size_t)HID * HID * 2);
    int*   deg     = (int*)alloc((size_t)N_NODES * 4);
    int*   rowptr  = (int*)alloc((size_t)(N_NODES + 1) * 4);
    int*   cursor  = (int*)alloc((size_t)N_NODES * 4);
    int*   csr_src = (int*)alloc((size_t)N_EDGES * 4);
    int*   bsum    = (int*)alloc(256 * 4);
    int*   gsum    = (int*)alloc(256 * 4);
    float* csums   = (float*)alloc((8 * KPAD1 + 256 + 256 + 256) * 4);
    float* colsum0_8 = csums;                    // 8 x 192 partial slots
    float* colsum1   = csums + 8 * KPAD1;        // 256
    float* colsum2   = csums + 8 * KPAD1 + 256;  // 256
    float* gvec      = csums + 8 * KPAD1 + 512;  // 256

    hipMemsetAsync(csums, 0, (8 * KPAD1 + 512) * 4, stream);
    hipMemsetAsync(deg, 0, (size_t)N_NODES * 4, stream);

    // all 4 weight packs (frag-major), one launch
    wt_fragmajor_all<<<(HID * KPAD1 + 3 * HID * HID + 255) / 256, 256, 0, stream>>>(
        m1aw, m1bw, m2aw, m2bw, Wf1, Wf2, Wf3, Wf4);

    // feat -> bf16 tiled
    feat_to_bf16<<<((size_t)N_NODES * (KPAD1 / 4) + 255) / 256, 256, 0, stream>>>(feat, featbf);
    // colsum0 partials (8-slot spread)
    colsum_feat8<<<1000, 192, 0, stream>>>(feat, colsum0_8);

    // CSR build (grouped by dst)
    degree_hist<<<N_EDGES / 256, 256, 0, stream>>>(dst, deg);
    block_degsum<<<NB, 256, 0, stream>>>(deg, bsum);
    scan_bsum<<<1, 256, 0, stream>>>(bsum, gsum);
    block_scan_write<<<NB, 256, 0, stream>>>(deg, gsum, rowptr, cursor);
    csr_fill<<<N_EDGES / 256, 256, 0, stream>>>(src, dst, cursor, csr_src);

    const int gtiles = (N_NODES + 15) / 16;   // 4 nodes/wave x 4 waves
    // xsum = bf16(feat + gather(feat)) — tiled, XCD-pinned, register-idx
    gather_v5<24, 3><<<gtiles * 8, 256, 0, stream>>>(featbf, rowptr, csr_src, xsum);

    const int gblocks = (N_NODES + 63) / 64;
    // node1 = relu(relu(xsum@W1+b1)@W2+b2), colsum1 fused   (A tiled24 -> tiled32 out)
    gemm_mlp8<KPAD1, 24, 32><<<gblocks, 512, 0, stream>>>(
        xsum, Wf1, m1ab, Wf2, m1bb, node1, colsum1, N_NODES);
    // y2 = bf16(node1 + gather(node1)) — tiled, XCD-pinned, register-idx
    gather_v5<32, 4><<<gtiles * 8, 256, 0, stream>>>(node1, rowptr, csr_src, y2);
    // node2 = relu(relu(y2@W3+b3)@W4+b4), colsum2 fused     (A tiled32 -> linear out)
    gemm_mlp8<HID, 32, 0><<<gblocks, 512, 0, stream>>>(
        y2, Wf3, m2ab, Wf4, m2bb, node2, colsum2, N_NODES);
    // graph head -> gvec = g_last
    graph_head<<<1, 256, 0, stream>>>(colsum0_8, colsum1, colsum2,
                                      g0w, g0b, g1w, g1b, g2w, g2b, glw, glb, gvec);
    // out = node2 + gvec
    final_add<<<((size_t)N_NODES * HID / 4 + 255) / 256, 256, 0, stream>>>(node2, gvec, out);
    (void)in_sizes; (void)n_in; (void)out_size; (void)ws_size;
}

// Round 8
// 465.846 us; speedup vs baseline: 1.1652x; 1.0054x over previous
//
#include <hip/hip_runtime.h>

#define N_NODES 50000
#define N_EDGES 800000
#define IN_DIM  162
#define HID     256
#define KPAD1   192   // IN_DIM padded to multiple of 32
#define NB      ((N_NODES + 255) / 256)   // 196 scan blocks

typedef __bf16 bf16;
typedef __bf16 bf16x8 __attribute__((ext_vector_type(8)));
typedef __bf16 bf16x4 __attribute__((ext_vector_type(4)));
typedef float  f32x4  __attribute__((ext_vector_type(4)));
typedef float  f32x8  __attribute__((ext_vector_type(8)));
typedef float  f32x16 __attribute__((ext_vector_type(16)));

// ---------------------------------------------------------------------------
// Frag-major weight pack: Wf element E holds the MFMA B-frag element
//   fb = jg*2+kk, E = ((ks*16 + fb)*64 + lane)*8 + e
//   -> W[k][n], n = jg*32 + (lane&31), k = ks*32 + kk*16 + (lane>>5)*8 + e
__device__ __forceinline__ void wf_one(const float* W, bf16* Wf, int K, int E)
{
    int e    = E & 7;
    int lane = (E >> 3) & 63;
    int fb   = (E >> 9) & 15;
    int ks   = E >> 13;
    int n = (fb >> 1) * 32 + (lane & 31);
    int k = ks * 32 + (fb & 1) * 16 + (lane >> 5) * 8 + e;
    Wf[E] = (k < K) ? (bf16)W[(size_t)k * HID + n] : (bf16)0.0f;
}

// ---------------------------------------------------------------------------
// prep_all: all independent preprocessing in ONE launch, partitioned by block.
//   [0, WTB)              : frag-major weight packs (4 matrices)
//   [WTB, WTB+FTB)        : feat f32 -> featbf bf16 tiled [8][N][24]
//   [.., +CSB)            : colsum0 partials (8-slot spread)
//   [.., +DGB)            : degree histogram
#define WTB  ((HID * KPAD1 + 3 * HID * HID + 255) / 256)          // 960
#define FTB  (((size_t)N_NODES * (KPAD1 / 4) + 255) / 256)        // 9375
#define CSB  1000
#define DGB  (N_EDGES / 256)                                      // 3125

__global__ void prep_all(const float* __restrict__ m1aw, const float* __restrict__ m1bw,
                         const float* __restrict__ m2aw, const float* __restrict__ m2bw,
                         bf16* __restrict__ Wf1, bf16* __restrict__ Wf2,
                         bf16* __restrict__ Wf3, bf16* __restrict__ Wf4,
                         const float* __restrict__ feat, bf16* __restrict__ featbf,
                         float* __restrict__ colsum8,
                         const int* __restrict__ dst, int* __restrict__ deg)
{
    const int b   = blockIdx.x;
    const int tid = threadIdx.x;

    if (b < WTB) {
        const int R1 = HID * KPAD1;
        const int R2 = HID * HID;
        int idx = b * 256 + tid;
        if (idx < R1)                 wf_one(m1aw, Wf1, IN_DIM, idx);
        else if (idx < R1 + R2)       wf_one(m1bw, Wf2, HID, idx - R1);
        else if (idx < R1 + 2 * R2)   wf_one(m2aw, Wf3, HID, idx - R1 - R2);
        else if (idx < R1 + 3 * R2)   wf_one(m2bw, Wf4, HID, idx - R1 - 2 * R2);
        return;
    }
    if (b < WTB + FTB) {
        int idx = (b - WTB) * 256 + tid;   // over N*KPAD1/4
        int r = idx / (KPAD1 / 4);
        int c4 = (idx - r * (KPAD1 / 4)) * 4;
        if (r >= N_NODES) return;
        bf16x4 o;
#pragma unroll
        for (int j = 0; j < 4; ++j) {
            int c = c4 + j;
            o[j] = (c < IN_DIM) ? (bf16)feat[(size_t)r * IN_DIM + c] : (bf16)0.0f;
        }
        int gch = c4 / 24;
        int off = c4 - gch * 24;
        *(bf16x4*)(featbf + ((size_t)gch * N_NODES + r) * 24 + off) = o;
        return;
    }
    if (b < WTB + FTB + CSB) {
        int csb = b - WTB - FTB;
        int c = tid;
        int r0 = csb * 50;
        if (c >= IN_DIM) return;
        float acc = 0.0f;
#pragma unroll 2
        for (int i = 0; i < 50; ++i) {
            int r = r0 + i;
            if (r < N_NODES) acc += feat[(size_t)r * IN_DIM + c];
        }
        atomicAdd(&colsum8[(csb & 7) * KPAD1 + c], acc);
        return;
    }
    {
        int e = (b - WTB - FTB - CSB) * 256 + tid;
        atomicAdd(&deg[dst[e]], 1);
    }
}

// ---------------------------------------------------------------------------
// CSR build (scan chain).
__global__ void block_degsum(const int* __restrict__ deg, int* __restrict__ bsum)
{
    __shared__ int s[256];
    int t = threadIdx.x;
    int idx = blockIdx.x * 256 + t;
    int v = (idx < N_NODES) ? deg[idx] : 0;
    s[t] = v;
    __syncthreads();
    for (int off = 128; off > 0; off >>= 1) {
        if (t < off) s[t] += s[t + off];
        __syncthreads();
    }
    if (t == 0) bsum[blockIdx.x] = s[0];
}

__global__ void scan_bsum(const int* __restrict__ bsum, int* __restrict__ gsum)
{
    __shared__ int s[256];
    int t = threadIdx.x;
    int v = (t < NB) ? bsum[t] : 0;
    s[t] = v;
    __syncthreads();
    for (int off = 1; off < 256; off <<= 1) {
        int u = (t >= off) ? s[t - off] : 0;
        __syncthreads();
        s[t] += u;
        __syncthreads();
    }
    gsum[t] = s[t] - v;
}

__global__ void block_scan_write(const int* __restrict__ deg, const int* __restrict__ gsum,
                                 int* __restrict__ rowptr, int* __restrict__ cursor)
{
    __shared__ int s[256];
    int t = threadIdx.x;
    int idx = blockIdx.x * 256 + t;
    int v = (idx < N_NODES) ? deg[idx] : 0;
    s[t] = v;
    __syncthreads();
    for (int off = 1; off < 256; off <<= 1) {
        int u = (t >= off) ? s[t - off] : 0;
        __syncthreads();
        s[t] += u;
        __syncthreads();
    }
    int excl = s[t] - v + gsum[blockIdx.x];
    if (idx < N_NODES) {
        rowptr[idx] = excl;
        cursor[idx] = excl;
    }
    if (idx == 0) rowptr[N_NODES] = N_EDGES;
}

__global__ void csr_fill(const int* __restrict__ src, const int* __restrict__ dst,
                         int* __restrict__ cursor, int* __restrict__ csr_src)
{
    int e = blockIdx.x * blockDim.x + threadIdx.x;
    int p = atomicAdd(&cursor[dst[e]], 1);
    csr_src[p] = src[e];
}

// ---------------------------------------------------------------------------
// Gather v5: tiled [8][N][CHUNK] input/output, XCD-pinned groups, in-register
// index list, masked unrolled row-load blocks.
template<int CHUNK, int NACT>
__launch_bounds__(256)
__global__ void gather_v5(const bf16* __restrict__ xin,
                          const int* __restrict__ rowptr,
                          const int* __restrict__ csr_src,
                          bf16* __restrict__ xout)
{
    const int g    = blockIdx.x & 7;
    const int tile = blockIdx.x >> 3;
    const int wv   = threadIdx.x >> 6;
    const int lane = threadIdx.x & 63;
    const int q    = lane >> 4;          // node within wave 0..3
    const int j    = lane & 15;          // idx slot
    const int e    = j >> 2;             // stripe 0..3
    const int c4   = j & 3;              // 16B chunk
    const int n    = tile * 16 + wv * 4 + q;
    const bool valid = (n < N_NODES);
    const bool act   = (c4 < NACT);
    const int  ce    = c4 * 8;
    const bf16* base = xin + (size_t)g * N_NODES * CHUNK;

    int r0 = 0, deg = 0;
    if (valid) {
        r0  = rowptr[n];
        deg = rowptr[n + 1] - r0;
    }

    int a0 = r0 + j;        if (a0 > N_EDGES - 1) a0 = N_EDGES - 1;
    int a1 = r0 + 16 + j;   if (a1 > N_EDGES - 1) a1 = N_EDGES - 1;
    const int i0 = csr_src[a0];
    const int i1 = csr_src[a1];

    f32x8 acc;
#pragma unroll
    for (int t = 0; t < 8; ++t) acc[t] = 0.0f;
    if (valid && e == 0 && act) {
        bf16x8 t0 = *(const bf16x8*)(base + (size_t)n * CHUNK + ce);
#pragma unroll
        for (int t = 0; t < 8; ++t) acc[t] = (float)t0[t];
    }

    const int lb = lane & ~3;

    // ---- block 1: positions 4e + k ----
    {
        const int s0 = __shfl(i0, lb + 0, 64);
        const int s1 = __shfl(i0, lb + 1, 64);
        const int s2 = __shfl(i0, lb + 2, 64);
        const int s3 = __shfl(i0, lb + 3, 64);
        const int p0 = 4 * e;
        if (act) {
            bf16x8 u0 = *(const bf16x8*)(base + (size_t)s0 * CHUNK + ce);
            bf16x8 u1 = *(const bf16x8*)(base + (size_t)s1 * CHUNK + ce);
            bf16x8 u2 = *(const bf16x8*)(base + (size_t)s2 * CHUNK + ce);
            bf16x8 u3 = *(const bf16x8*)(base + (size_t)s3 * CHUNK + ce);
            if (p0 + 0 < deg) {
#pragma unroll
                for (int t = 0; t < 8; ++t) acc[t] += (float)u0[t];
            }
            if (p0 + 1 < deg) {
#pragma unroll
                for (int t = 0; t < 8; ++t) acc[t] += (float)u1[t];
            }
            if (p0 + 2 < deg) {
#pragma unroll
                for (int t = 0; t < 8; ++t) acc[t] += (float)u2[t];
            }
            if (p0 + 3 < deg) {
#pragma unroll
                for (int t = 0; t < 8; ++t) acc[t] += (float)u3[t];
            }
        }
    }

    // ---- block 2: positions 16 + 4e + k, stripe-gated ----
    {
        const int s0 = __shfl(i1, lb + 0, 64);
        const int s1 = __shfl(i1, lb + 1, 64);
        const int s2 = __shfl(i1, lb + 2, 64);
        const int s3 = __shfl(i1, lb + 3, 64);
        const int p0 = 16 + 4 * e;
        if (act && p0 < deg) {
            bf16x8 u0 = *(const bf16x8*)(base + (size_t)s0 * CHUNK + ce);
            bf16x8 u1 = *(const bf16x8*)(base + (size_t)s1 * CHUNK + ce);
            bf16x8 u2 = *(const bf16x8*)(base + (size_t)s2 * CHUNK + ce);
            bf16x8 u3 = *(const bf16x8*)(base + (size_t)s3 * CHUNK + ce);
            {
#pragma unroll
                for (int t = 0; t < 8; ++t) acc[t] += (float)u0[t];
            }
            if (p0 + 1 < deg) {
#pragma unroll
                for (int t = 0; t < 8; ++t) acc[t] += (float)u1[t];
            }
            if (p0 + 2 < deg) {
#pragma unroll
                for (int t = 0; t < 8; ++t) acc[t] += (float)u2[t];
            }
            if (p0 + 3 < deg) {
#pragma unroll
                for (int t = 0; t < 8; ++t) acc[t] += (float)u3[t];
            }
        }
    }

    // ---- rare tail: deg > 32 ----
    for (int p = 32 + e; p < deg; p += 4) {
        const int s = csr_src[r0 + p];
        if (act) {
            bf16x8 u = *(const bf16x8*)(base + (size_t)s * CHUNK + ce);
#pragma unroll
            for (int t = 0; t < 8; ++t) acc[t] += (float)u[t];
        }
    }

#pragma unroll
    for (int t = 0; t < 8; ++t) {
        acc[t] += __shfl_xor(acc[t], 4, 64);
        acc[t] += __shfl_xor(acc[t], 8, 64);
    }

    if (valid && e == 0 && act) {
        bf16x8 o;
#pragma unroll
        for (int t = 0; t < 8; ++t) o[t] = (bf16)acc[t];
        __builtin_nontemporal_store(o,
            (bf16x8*)(xout + ((size_t)g * N_NODES + n) * CHUNK + ce));
    }
}

// ---------------------------------------------------------------------------
// Fused GIN MLP v9: out = relu(relu(X@W1+b1)@W2+b2), colsum fused.
// 4 waves/block, 64 rows/block; wave w owns col range [w*64, w*64+64) over
// ALL 64 rows -> per-wave tile 64x64, acc[2][2] (named, static). Each B-frag
// feeds 4 MFMAs (2x arithmetic intensity per B-load vs round 7); chip B-frag
// traffic halves. Depth-1 rotation prefetch of (a0,a1,b0,b1).
// H in LDS (32KB), (row&31)<<4 XOR swizzle (bank-conflict 0, measured r7).
// ACHUNK: 0 = X linear [M][KPAD]; else X tiled [KPAD/ACHUNK][N_NODES][ACHUNK].
// OCHUNK: 0 = out linear [M][HID]; else out tiled [HID/32][N_NODES][32].
template<int KPAD, int ACHUNK, int OCHUNK>
__launch_bounds__(256)
__global__ void gemm_mlp4(const bf16* __restrict__ X,
                          const bf16* __restrict__ Wf1,
                          const float* __restrict__ bias1,
                          const bf16* __restrict__ Wf2,
                          const float* __restrict__ bias2,
                          bf16* __restrict__ out_bf,
                          float* __restrict__ colsum,   // nullable
                          int M)
{
    __shared__ __align__(128) bf16 sH[64 * HID];   // 32 KB
    __shared__ float cs[HID];

    const int tid  = threadIdx.x;
    const int w    = tid >> 6;     // col quarter 0..3
    const int lane = tid & 63;
    const int p    = lane >> 5;
    const int cn   = lane & 31;
    const int m_base = blockIdx.x * 64;
    const int jg0  = w * 2;

    int ar0 = m_base + cn;        if (ar0 >= M) ar0 = M - 1;
    int ar1 = m_base + 32 + cn;   if (ar1 >= M) ar1 = M - 1;

    f32x16 acc00, acc01, acc10, acc11;   // [rowhalf][jj]
#pragma unroll
    for (int r = 0; r < 16; ++r) { acc00[r] = 0.0f; acc01[r] = 0.0f; acc10[r] = 0.0f; acc11[r] = 0.0f; }

    // A address for k-step t (t = ks*2+kk, 16 k per step)
    auto aptr = [&](int row, int t) -> const bf16* {
        const int e = t * 16 + p * 8;
        if constexpr (ACHUNK == 0) {
            return X + (size_t)row * KPAD + e;
        } else {
            const int gch = e / ACHUNK;
            const int off = e - gch * ACHUNK;
            return X + ((size_t)gch * N_NODES + row) * ACHUNK + off;
        }
    };
    auto bptr = [&](const bf16* Wf, int jg, int t) -> const bf16* {
        const int ks = t >> 1, kk = t & 1;
        return Wf + (((ks * 16 + jg * 2 + kk) * 64) + lane) * 8;
    };

    // ---- phase 1: acc = X @ W1, depth-1 rotation prefetch ----
    constexpr int T1 = KPAD / 16;
    {
        bf16x8 a0 = *(const bf16x8*)aptr(ar0, 0);
        bf16x8 a1 = *(const bf16x8*)aptr(ar1, 0);
        bf16x8 b0 = *(const bf16x8*)bptr(Wf1, jg0, 0);
        bf16x8 b1 = *(const bf16x8*)bptr(Wf1, jg0 + 1, 0);
#pragma unroll
        for (int t = 0; t < T1; ++t) {
            bf16x8 na0 = a0, na1 = a1, nb0 = b0, nb1 = b1;
            if (t + 1 < T1) {
                na0 = *(const bf16x8*)aptr(ar0, t + 1);
                na1 = *(const bf16x8*)aptr(ar1, t + 1);
                nb0 = *(const bf16x8*)bptr(Wf1, jg0, t + 1);
                nb1 = *(const bf16x8*)bptr(Wf1, jg0 + 1, t + 1);
            }
            acc00 = __builtin_amdgcn_mfma_f32_32x32x16_bf16(a0, b0, acc00, 0, 0, 0);
            acc01 = __builtin_amdgcn_mfma_f32_32x32x16_bf16(a0, b1, acc01, 0, 0, 0);
            acc10 = __builtin_amdgcn_mfma_f32_32x32x16_bf16(a1, b0, acc10, 0, 0, 0);
            acc11 = __builtin_amdgcn_mfma_f32_32x32x16_bf16(a1, b1, acc11, 0, 0, 0);
            a0 = na0; a1 = na1; b0 = nb0; b1 = nb1;
        }
    }

    // ---- epilogue 1: H = relu(acc + b1) -> LDS, (row&31)<<4 swizzle ----
    char* sHb = (char*)sH;
#pragma unroll
    for (int rh = 0; rh < 2; ++rh) {
#pragma unroll
        for (int jj = 0; jj < 2; ++jj) {
            const int col = w * 64 + jj * 32 + cn;
            const float bv = bias1[col];
#pragma unroll
            for (int r = 0; r < 16; ++r) {
                const int rowl = (r & 3) + 8 * (r >> 2) + 4 * p;
                const int rowf = rh * 32 + rowl;
                float v = (rh == 0 ? (jj == 0 ? acc00[r] : acc01[r])
                                   : (jj == 0 ? acc10[r] : acc11[r])) + bv;
                v = v > 0.0f ? v : 0.0f;
                int ba = rowf * (HID * 2) + col * 2;
                ba ^= (rowf & 31) << 4;
                *(bf16*)(sHb + ba) = (bf16)v;
            }
        }
    }
    __syncthreads();

    // ---- phase 2: acc = H @ W2 (A from LDS), rotation prefetch on B ----
#pragma unroll
    for (int r = 0; r < 16; ++r) { acc00[r] = 0.0f; acc01[r] = 0.0f; acc10[r] = 0.0f; acc11[r] = 0.0f; }

    const int hr0 = cn, hr1 = 32 + cn;
    const int hs0 = (hr0 & 31) << 4, hs1 = (hr1 & 31) << 4;
    constexpr int T2 = HID / 16;
    {
        bf16x8 b0 = *(const bf16x8*)bptr(Wf2, jg0, 0);
        bf16x8 b1 = *(const bf16x8*)bptr(Wf2, jg0 + 1, 0);
#pragma unroll
        for (int t = 0; t < T2; ++t) {
            bf16x8 nb0 = b0, nb1 = b1;
            if (t + 1 < T2) {
                nb0 = *(const bf16x8*)bptr(Wf2, jg0, t + 1);
                nb1 = *(const bf16x8*)bptr(Wf2, jg0 + 1, t + 1);
            }
            const int kb = (t * 16 + p * 8) * 2;
            bf16x8 a0 = *(const bf16x8*)(sHb + ((hr0 * (HID * 2) + kb) ^ hs0));
            bf16x8 a1 = *(const bf16x8*)(sHb + ((hr1 * (HID * 2) + kb) ^ hs1));
            acc00 = __builtin_amdgcn_mfma_f32_32x32x16_bf16(a0, b0, acc00, 0, 0, 0);
            acc01 = __builtin_amdgcn_mfma_f32_32x32x16_bf16(a0, b1, acc01, 0, 0, 0);
            acc10 = __builtin_amdgcn_mfma_f32_32x32x16_bf16(a1, b0, acc10, 0, 0, 0);
            acc11 = __builtin_amdgcn_mfma_f32_32x32x16_bf16(a1, b1, acc11, 0, 0, 0);
            b0 = nb0; b1 = nb1;
        }
    }

    // ---- epilogue 2: bias2 + relu + store + colsum ----
    if (colsum) {
        if (tid < HID) cs[tid] = 0.0f;
        __syncthreads();
    }

#pragma unroll
    for (int jj = 0; jj < 2; ++jj) {
        const int jg  = jg0 + jj;
        const int col = jg * 32 + cn;
        const float bv = bias2[col];
        float part = 0.0f;
#pragma unroll
        for (int rh = 0; rh < 2; ++rh) {
#pragma unroll
            for (int r = 0; r < 16; ++r) {
                int rl = rh * 32 + (r & 3) + 8 * (r >> 2) + 4 * p;
                int mo = m_base + rl;
                if (mo < M) {
                    float v = (rh == 0 ? (jj == 0 ? acc00[r] : acc01[r])
                                       : (jj == 0 ? acc10[r] : acc11[r])) + bv;
                    v = v > 0.0f ? v : 0.0f;
                    if constexpr (OCHUNK == 0)
                        out_bf[(size_t)mo * HID + col] = (bf16)v;
                    else
                        out_bf[((size_t)jg * N_NODES + mo) * OCHUNK + cn] = (bf16)v;
                    part += v;
                }
            }
        }
        if (colsum) {
            part += __shfl_xor(part, 32, 64);   // combine the two p-halves
            if (p == 0) atomicAdd(&cs[col], part);
        }
    }

    if (colsum) {
        __syncthreads();
        if (tid < HID) atomicAdd(&colsum[tid], cs[tid]);
    }
}

// ---------------------------------------------------------------------------
// Graph head: three GEMVs + sum + final GEMV, single block of 256 threads.
__global__ void graph_head(const float* __restrict__ cs0_8,
                           const float* __restrict__ cs1,
                           const float* __restrict__ cs2,
                           const float* __restrict__ g0w, const float* __restrict__ g0b,
                           const float* __restrict__ g1w, const float* __restrict__ g1b,
                           const float* __restrict__ g2w, const float* __restrict__ g2b,
                           const float* __restrict__ glw, const float* __restrict__ glb,
                           float* __restrict__ gvec)
{
    __shared__ float v0[IN_DIM], v1[HID], v2[HID], gs[HID];
    int t = threadIdx.x;
    if (t < IN_DIM) {
        float s = 0.0f;
#pragma unroll
        for (int i = 0; i < 8; ++i) s += cs0_8[i * KPAD1 + t];
        v0[t] = s;
    }
    v1[t] = cs1[t];
    v2[t] = cs2[t];
    __syncthreads();

    float a0 = 0.0f, a1 = 0.0f, a2 = 0.0f;
    for (int k = 0; k < IN_DIM; ++k) a0 += v0[k] * g0w[k * HID + t];
    for (int k = 0; k < HID; ++k) {
        a1 += v1[k] * g1w[k * HID + t];
        a2 += v2[k] * g2w[k * HID + t];
    }
    float e0 = fmaxf(a0 + g0b[t], 0.0f);
    float e1 = fmaxf(a1 + g1b[t], 0.0f);
    float e2 = fmaxf(a2 + g2b[t], 0.0f);
    gs[t] = e0 + e1 + e2;
    __syncthreads();

    float a3 = 0.0f;
    for (int k = 0; k < HID; ++k) a3 += gs[k] * glw[k * HID + t];
    gvec[t] = fmaxf(a3 + glb[t], 0.0f);
}

// ---------------------------------------------------------------------------
// out[n,c] = node2[n,c](bf16) + gvec[c] (f32 out); 4 elements per thread.
__global__ void final_add(const bf16* __restrict__ node2,
                          const float* __restrict__ gvec,
                          float* __restrict__ out)
{
    int idx = blockIdx.x * blockDim.x + threadIdx.x;
    size_t base = (size_t)idx * 4;
    int c = (int)(base & (HID - 1));
    bf16x4 v = *(const bf16x4*)(node2 + base);
    f32x4 g = *(const f32x4*)(gvec + c);
    f32x4 o;
#pragma unroll
    for (int j = 0; j < 4; ++j) o[j] = (float)v[j] + g[j];
    *(f32x4*)(out + base) = o;
}

// ---------------------------------------------------------------------------
extern "C" void kernel_launch(void* const* d_in, const int* in_sizes, int n_in,
                              void* d_out, int out_size, void* d_ws, size_t ws_size,
                              hipStream_t stream)
{
    const float* feat = (const float*)d_in[0];
    const int*   ei   = (const int*)d_in[1];
    const int*   src  = ei;
    const int*   dst  = ei + N_EDGES;
    const float* g0w = (const float*)d_in[2],  *g0b = (const float*)d_in[3];
    const float* g1w = (const float*)d_in[4],  *g1b = (const float*)d_in[5];
    const float* g2w = (const float*)d_in[6],  *g2b = (const float*)d_in[7];
    const float* glw = (const float*)d_in[8],  *glb = (const float*)d_in[9];
    const float* m1aw = (const float*)d_in[10], *m1ab = (const float*)d_in[11];
    const float* m1bw = (const float*)d_in[12], *m1bb = (const float*)d_in[13];
    const float* m2aw = (const float*)d_in[14], *m2ab = (const float*)d_in[15];
    const float* m2bw = (const float*)d_in[16], *m2bb = (const float*)d_in[17];
    float* out = (float*)d_out;

    char* ws = (char*)d_ws;
    size_t off = 0;
    auto alloc = [&](size_t bytes) -> void* {
        void* p = ws + off;
        off += (bytes + 255) & ~(size_t)255;
        return p;
    };
    bf16*  featbf = (bf16*)alloc((size_t)N_NODES * KPAD1 * 2);   // tiled [8][N][24]
    bf16*  xsum  = (bf16*) alloc((size_t)N_NODES * KPAD1 * 2);   // tiled [8][N][24]
    bf16*  y2    = (bf16*) alloc((size_t)N_NODES * HID * 2);     // tiled [8][N][32]
    bf16*  node2 = (bf16*) alloc((size_t)N_NODES * HID * 2);     // linear
    bf16*  node1 = (bf16*) alloc((size_t)N_NODES * HID * 2);     // tiled [8][N][32]
    bf16*  Wf1   = (bf16*) alloc((size_t)HID * KPAD1 * 2);       // frag-major
    bf16*  Wf2   = (bf16*) alloc((size_t)HID * HID * 2);
    bf16*  Wf3   = (bf16*) alloc((size_t)HID * HID * 2);
    bf16*  Wf4   = (bf16*) alloc((size_t)HID * HID * 2);
    int*   deg     = (int*)alloc((size_t)N_NODES * 4);
    int*   rowptr  = (int*)alloc((size_t)(N_NODES + 1) * 4);
    int*   cursor  = (int*)alloc((size_t)N_NODES * 4);
    int*   csr_src = (int*)alloc((size_t)N_EDGES * 4);
    int*   bsum    = (int*)alloc(256 * 4);
    int*   gsum    = (int*)alloc(256 * 4);
    float* csums   = (float*)alloc((8 * KPAD1 + 256 + 256 + 256) * 4);
    float* colsum0_8 = csums;                    // 8 x 192 partial slots
    float* colsum1   = csums + 8 * KPAD1;        // 256
    float* colsum2   = csums + 8 * KPAD1 + 256;  // 256
    float* gvec      = csums + 8 * KPAD1 + 512;  // 256

    hipMemsetAsync(csums, 0, (8 * KPAD1 + 512) * 4, stream);
    hipMemsetAsync(deg, 0, (size_t)N_NODES * 4, stream);

    // all independent preprocessing in one launch
    prep_all<<<WTB + FTB + CSB + DGB, 256, 0, stream>>>(
        m1aw, m1bw, m2aw, m2bw, Wf1, Wf2, Wf3, Wf4,
        feat, featbf, colsum0_8, dst, deg);

    // CSR scan chain
    block_degsum<<<NB, 256, 0, stream>>>(deg, bsum);
    scan_bsum<<<1, 256, 0, stream>>>(bsum, gsum);
    block_scan_write<<<NB, 256, 0, stream>>>(deg, gsum, rowptr, cursor);
    csr_fill<<<N_EDGES / 256, 256, 0, stream>>>(src, dst, cursor, csr_src);

    const int gtiles = (N_NODES + 15) / 16;   // 4 nodes/wave x 4 waves
    // xsum = bf16(feat + gather(feat)) — tiled, XCD-pinned, register-idx
    gather_v5<24, 3><<<gtiles * 8, 256, 0, stream>>>(featbf, rowptr, csr_src, xsum);

    const int gblocks = (N_NODES + 63) / 64;
    // node1 = relu(relu(xsum@W1+b1)@W2+b2), colsum1 fused   (A tiled24 -> tiled32 out)
    gemm_mlp4<KPAD1, 24, 32><<<gblocks, 256, 0, stream>>>(
        xsum, Wf1, m1ab, Wf2, m1bb, node1, colsum1, N_NODES);
    // y2 = bf16(node1 + gather(node1)) — tiled, XCD-pinned, register-idx
    gather_v5<32, 4><<<gtiles * 8, 256, 0, stream>>>(node1, rowptr, csr_src, y2);
    // node2 = relu(relu(y2@W3+b3)@W4+b4), colsum2 fused     (A tiled32 -> linear out)
    gemm_mlp4<HID, 32, 0><<<gblocks, 256, 0, stream>>>(
        y2, Wf3, m2ab, Wf4, m2bb, node2, colsum2, N_NODES);
    // graph head -> gvec = g_last
    graph_head<<<1, 256, 0, stream>>>(colsum0_8, colsum1, colsum2,
                                      g0w, g0b, g1w, g1b, g2w, g2b, glw, glb, gvec);
    // out = node2 + gvec
    final_add<<<((size_t)N_NODES * HID / 4 + 255) / 256, 256, 0, stream>>>(node2, gvec, out);
    (void)in_sizes; (void)n_in; (void)out_size; (void)ws_size;
}

// Round 9
// 455.323 us; speedup vs baseline: 1.1921x; 1.0231x over previous
//
#include <hip/hip_runtime.h>

#define N_NODES 50000
#define N_EDGES 800000
#define IN_DIM  162
#define HID     256
#define KPAD1   192   // IN_DIM padded to multiple of 32
#define NB      ((N_NODES + 255) / 256)   // 196 scan blocks

typedef __bf16 bf16;
typedef __bf16 bf16x8 __attribute__((ext_vector_type(8)));
typedef __bf16 bf16x4 __attribute__((ext_vector_type(4)));
typedef float  f32x4  __attribute__((ext_vector_type(4)));
typedef float  f32x8  __attribute__((ext_vector_type(8)));
typedef float  f32x16 __attribute__((ext_vector_type(16)));

// ---------------------------------------------------------------------------
// Frag-major weight pack: Wf element E holds the MFMA B-frag element
//   fb = jg*2+kk, E = ((ks*16 + fb)*64 + lane)*8 + e
//   -> W[k][n], n = jg*32 + (lane&31), k = ks*32 + kk*16 + (lane>>5)*8 + e
__device__ __forceinline__ void wf_one(const float* W, bf16* Wf, int K, int E)
{
    int e    = E & 7;
    int lane = (E >> 3) & 63;
    int fb   = (E >> 9) & 15;
    int ks   = E >> 13;
    int n = (fb >> 1) * 32 + (lane & 31);
    int k = ks * 32 + (fb & 1) * 16 + (lane >> 5) * 8 + e;
    Wf[E] = (k < K) ? (bf16)W[(size_t)k * HID + n] : (bf16)0.0f;
}

// ---------------------------------------------------------------------------
// prep_all v2: one launch, partitioned by block.
//   [0, WTB)       : frag-major weight packs (4 matrices)
//   [WTB, +FPB)    : feat prep: single-read convert + f32 colsum + coalesced
//                    group-major tiled writes (64 rows per block, LDS-staged)
//   [.., +DGB)     : degree histogram
#define WTB  ((HID * KPAD1 + 3 * HID * HID + 255) / 256)          // 960
#define FPB  ((N_NODES + 63) / 64)                                // 782
#define DGB  (N_EDGES / 256)                                      // 3125

__global__ void prep_all(const float* __restrict__ m1aw, const float* __restrict__ m1bw,
                         const float* __restrict__ m2aw, const float* __restrict__ m2bw,
                         bf16* __restrict__ Wf1, bf16* __restrict__ Wf2,
                         bf16* __restrict__ Wf3, bf16* __restrict__ Wf4,
                         const float* __restrict__ feat, bf16* __restrict__ featbf,
                         float* __restrict__ colsum8,
                         const int* __restrict__ dst, int* __restrict__ deg)
{
    __shared__ bf16  tile[64][208];   // padded; 16B-aligned rows (416B stride)
    __shared__ float lcs[KPAD1];

    const int b   = blockIdx.x;
    const int tid = threadIdx.x;

    if (b < WTB) {
        const int R1 = HID * KPAD1;
        const int R2 = HID * HID;
        int idx = b * 256 + tid;
        if (idx < R1)                 wf_one(m1aw, Wf1, IN_DIM, idx);
        else if (idx < R1 + R2)       wf_one(m1bw, Wf2, HID, idx - R1);
        else if (idx < R1 + 2 * R2)   wf_one(m2aw, Wf3, HID, idx - R1 - R2);
        else if (idx < R1 + 3 * R2)   wf_one(m2bw, Wf4, HID, idx - R1 - 2 * R2);
        return;
    }
    if (b < WTB + FPB) {
        const int fp = b - WTB;
        const int r0 = fp * 64;
        for (int i = tid; i < KPAD1; i += 256) lcs[i] = 0.0f;
        __syncthreads();

        // phase A: read feat once (coalesced f32x4-ish), convert, LDS colsum
        // 64 rows x 48 chunks of 4 cols, row-major task index.
#pragma unroll
        for (int i = 0; i < 12; ++i) {
            int idx = i * 256 + tid;          // [0, 3072)
            int rl  = idx / 48;
            int ch  = idx - rl * 48;
            int c4  = ch * 4;
            int r   = r0 + rl;
            bf16x4 o;
            if (r < N_NODES) {
#pragma unroll
                for (int j = 0; j < 4; ++j) {
                    int c = c4 + j;
                    float f = (c < IN_DIM) ? feat[(size_t)r * IN_DIM + c] : 0.0f;
                    o[j] = (bf16)f;
                    if (c < IN_DIM) atomicAdd(&lcs[c], f);
                }
            } else {
#pragma unroll
                for (int j = 0; j < 4; ++j) o[j] = (bf16)0.0f;
            }
            *(bf16x4*)(&tile[rl][c4]) = o;
        }
        __syncthreads();

        // phase B: group-major coalesced writes: 8 groups x 64 rows x 24 cols
        // = 1536 x 16B chunks, contiguous per group.
#pragma unroll
        for (int i = 0; i < 6; ++i) {
            int m  = i * 256 + tid;           // [0, 1536)
            int g  = m / 192;                 // 192 chunks per group
            int wg = m - g * 192;
            int eo = wg * 8;                  // elem offset in 64x24 group block
            int rl = eo / 24;
            int cc = eo - rl * 24;
            int r  = r0 + rl;
            if (r < N_NODES) {
                bf16x8 o = *(const bf16x8*)(&tile[rl][g * 24 + cc]);
                *(bf16x8*)(featbf + ((size_t)g * N_NODES + r0) * 24 + (size_t)rl * 24 + cc) = o;
            }
        }

        // phase C: one global atomic per column
        if (tid < IN_DIM) atomicAdd(&colsum8[(fp & 7) * KPAD1 + tid], lcs[tid]);
        return;
    }
    {
        int e = (b - WTB - FPB) * 256 + tid;
        atomicAdd(&deg[dst[e]], 1);
    }
}

// ---------------------------------------------------------------------------
// CSR build (scan chain).
__global__ void block_degsum(const int* __restrict__ deg, int* __restrict__ bsum)
{
    __shared__ int s[256];
    int t = threadIdx.x;
    int idx = blockIdx.x * 256 + t;
    int v = (idx < N_NODES) ? deg[idx] : 0;
    s[t] = v;
    __syncthreads();
    for (int off = 128; off > 0; off >>= 1) {
        if (t < off) s[t] += s[t + off];
        __syncthreads();
    }
    if (t == 0) bsum[blockIdx.x] = s[0];
}

__global__ void scan_bsum(const int* __restrict__ bsum, int* __restrict__ gsum)
{
    __shared__ int s[256];
    int t = threadIdx.x;
    int v = (t < NB) ? bsum[t] : 0;
    s[t] = v;
    __syncthreads();
    for (int off = 1; off < 256; off <<= 1) {
        int u = (t >= off) ? s[t - off] : 0;
        __syncthreads();
        s[t] += u;
        __syncthreads();
    }
    gsum[t] = s[t] - v;
}

__global__ void block_scan_write(const int* __restrict__ deg, const int* __restrict__ gsum,
                                 int* __restrict__ rowptr, int* __restrict__ cursor)
{
    __shared__ int s[256];
    int t = threadIdx.x;
    int idx = blockIdx.x * 256 + t;
    int v = (idx < N_NODES) ? deg[idx] : 0;
    s[t] = v;
    __syncthreads();
    for (int off = 1; off < 256; off <<= 1) {
        int u = (t >= off) ? s[t - off] : 0;
        __syncthreads();
        s[t] += u;
        __syncthreads();
    }
    int excl = s[t] - v + gsum[blockIdx.x];
    if (idx < N_NODES) {
        rowptr[idx] = excl;
        cursor[idx] = excl;
    }
    if (idx == 0) rowptr[N_NODES] = N_EDGES;
}

__global__ void csr_fill(const int* __restrict__ src, const int* __restrict__ dst,
                         int* __restrict__ cursor, int* __restrict__ csr_src)
{
    int e = blockIdx.x * blockDim.x + threadIdx.x;
    int p = atomicAdd(&cursor[dst[e]], 1);
    csr_src[p] = src[e];
}

// ---------------------------------------------------------------------------
// Gather v5: tiled [8][N][CHUNK] input/output, XCD-pinned groups, in-register
// index list, masked unrolled row-load blocks.
template<int CHUNK, int NACT>
__launch_bounds__(256)
__global__ void gather_v5(const bf16* __restrict__ xin,
                          const int* __restrict__ rowptr,
                          const int* __restrict__ csr_src,
                          bf16* __restrict__ xout)
{
    const int g    = blockIdx.x & 7;
    const int tile = blockIdx.x >> 3;
    const int wv   = threadIdx.x >> 6;
    const int lane = threadIdx.x & 63;
    const int q    = lane >> 4;          // node within wave 0..3
    const int j    = lane & 15;          // idx slot
    const int e    = j >> 2;             // stripe 0..3
    const int c4   = j & 3;              // 16B chunk
    const int n    = tile * 16 + wv * 4 + q;
    const bool valid = (n < N_NODES);
    const bool act   = (c4 < NACT);
    const int  ce    = c4 * 8;
    const bf16* base = xin + (size_t)g * N_NODES * CHUNK;

    int r0 = 0, deg = 0;
    if (valid) {
        r0  = rowptr[n];
        deg = rowptr[n + 1] - r0;
    }

    int a0 = r0 + j;        if (a0 > N_EDGES - 1) a0 = N_EDGES - 1;
    int a1 = r0 + 16 + j;   if (a1 > N_EDGES - 1) a1 = N_EDGES - 1;
    const int i0 = csr_src[a0];
    const int i1 = csr_src[a1];

    f32x8 acc;
#pragma unroll
    for (int t = 0; t < 8; ++t) acc[t] = 0.0f;
    if (valid && e == 0 && act) {
        bf16x8 t0 = *(const bf16x8*)(base + (size_t)n * CHUNK + ce);
#pragma unroll
        for (int t = 0; t < 8; ++t) acc[t] = (float)t0[t];
    }

    const int lb = lane & ~3;

    // ---- block 1: positions 4e + k ----
    {
        const int s0 = __shfl(i0, lb + 0, 64);
        const int s1 = __shfl(i0, lb + 1, 64);
        const int s2 = __shfl(i0, lb + 2, 64);
        const int s3 = __shfl(i0, lb + 3, 64);
        const int p0 = 4 * e;
        if (act) {
            bf16x8 u0 = *(const bf16x8*)(base + (size_t)s0 * CHUNK + ce);
            bf16x8 u1 = *(const bf16x8*)(base + (size_t)s1 * CHUNK + ce);
            bf16x8 u2 = *(const bf16x8*)(base + (size_t)s2 * CHUNK + ce);
            bf16x8 u3 = *(const bf16x8*)(base + (size_t)s3 * CHUNK + ce);
            if (p0 + 0 < deg) {
#pragma unroll
                for (int t = 0; t < 8; ++t) acc[t] += (float)u0[t];
            }
            if (p0 + 1 < deg) {
#pragma unroll
                for (int t = 0; t < 8; ++t) acc[t] += (float)u1[t];
            }
            if (p0 + 2 < deg) {
#pragma unroll
                for (int t = 0; t < 8; ++t) acc[t] += (float)u2[t];
            }
            if (p0 + 3 < deg) {
#pragma unroll
                for (int t = 0; t < 8; ++t) acc[t] += (float)u3[t];
            }
        }
    }

    // ---- block 2: positions 16 + 4e + k, stripe-gated ----
    {
        const int s0 = __shfl(i1, lb + 0, 64);
        const int s1 = __shfl(i1, lb + 1, 64);
        const int s2 = __shfl(i1, lb + 2, 64);
        const int s3 = __shfl(i1, lb + 3, 64);
        const int p0 = 16 + 4 * e;
        if (act && p0 < deg) {
            bf16x8 u0 = *(const bf16x8*)(base + (size_t)s0 * CHUNK + ce);
            bf16x8 u1 = *(const bf16x8*)(base + (size_t)s1 * CHUNK + ce);
            bf16x8 u2 = *(const bf16x8*)(base + (size_t)s2 * CHUNK + ce);
            bf16x8 u3 = *(const bf16x8*)(base + (size_t)s3 * CHUNK + ce);
            {
#pragma unroll
                for (int t = 0; t < 8; ++t) acc[t] += (float)u0[t];
            }
            if (p0 + 1 < deg) {
#pragma unroll
                for (int t = 0; t < 8; ++t) acc[t] += (float)u1[t];
            }
            if (p0 + 2 < deg) {
#pragma unroll
                for (int t = 0; t < 8; ++t) acc[t] += (float)u2[t];
            }
            if (p0 + 3 < deg) {
#pragma unroll
                for (int t = 0; t < 8; ++t) acc[t] += (float)u3[t];
            }
        }
    }

    // ---- rare tail: deg > 32 ----
    for (int p = 32 + e; p < deg; p += 4) {
        const int s = csr_src[r0 + p];
        if (act) {
            bf16x8 u = *(const bf16x8*)(base + (size_t)s * CHUNK + ce);
#pragma unroll
            for (int t = 0; t < 8; ++t) acc[t] += (float)u[t];
        }
    }

#pragma unroll
    for (int t = 0; t < 8; ++t) {
        acc[t] += __shfl_xor(acc[t], 4, 64);
        acc[t] += __shfl_xor(acc[t], 8, 64);
    }

    if (valid && e == 0 && act) {
        bf16x8 o;
#pragma unroll
        for (int t = 0; t < 8; ++t) o[t] = (bf16)acc[t];
        __builtin_nontemporal_store(o,
            (bf16x8*)(xout + ((size_t)g * N_NODES + n) * CHUNK + ce));
    }
}

// ---------------------------------------------------------------------------
// Fused GIN MLP v10 "gemm_mlp32": out = relu(relu(X@W1+b1)@W2+b2).
// 32-row blocks, 8 waves; wave w owns cols [w*32, w*32+32) over all 32 rows
// -> 32x32 per wave, acc = 1 f32x16. Grid = 1563 blocks = 12512 waves (2x r7,
// 4x r8) — maximize TLP for this latency-bound regime (r7 vs r8 A/B evidence).
// B-frags coalesced from frag-major Wf (L2-resident); no K-loop barriers.
// H in LDS (16KB), (row&31)<<4 XOR swizzle (bank-conflict 0 measured r7/r8).
// colsum (nullable) is 8-slotted [8][HID]; slot = blockIdx&7.
// ACHUNK: 0 = X linear [M][KPAD]; else X tiled [KPAD/ACHUNK][N_NODES][ACHUNK].
// OCHUNK: 0 = out linear [M][HID]; else out tiled [HID/32][N_NODES][32].
template<int KPAD, int ACHUNK, int OCHUNK>
__launch_bounds__(512)
__global__ void gemm_mlp32(const bf16* __restrict__ X,
                           const bf16* __restrict__ Wf1,
                           const float* __restrict__ bias1,
                           const bf16* __restrict__ Wf2,
                           const float* __restrict__ bias2,
                           bf16* __restrict__ out_bf,
                           float* __restrict__ colsum8,  // [8][HID] or null
                           int M)
{
    __shared__ __align__(128) bf16 sH[32 * HID];   // 16 KB

    const int tid  = threadIdx.x;
    const int w    = tid >> 6;     // col group 0..7
    const int lane = tid & 63;
    const int p    = lane >> 5;
    const int cn   = lane & 31;
    const int m_base = blockIdx.x * 32;

    int arow = m_base + cn;
    if (arow >= M) arow = M - 1;   // clamp (stores guarded)

    f32x16 acc;
#pragma unroll
    for (int r = 0; r < 16; ++r) acc[r] = 0.0f;

    // ---- phase 1: acc = X @ W1 (barrier-free) ----
    constexpr int T1 = KPAD / 16;
#pragma unroll
    for (int t = 0; t < T1; ++t) {
        bf16x8 a;
        {
            const int e = t * 16 + p * 8;
            if constexpr (ACHUNK == 0) {
                a = *(const bf16x8*)(X + (size_t)arow * KPAD + e);
            } else {
                const int gch = e / ACHUNK;
                const int off = e - gch * ACHUNK;
                a = *(const bf16x8*)(X + ((size_t)gch * N_NODES + arow) * ACHUNK + off);
            }
        }
        bf16x8 b = *(const bf16x8*)(Wf1 + ((((t >> 1) * 16 + w * 2 + (t & 1)) * 64) + lane) * 8);
        acc = __builtin_amdgcn_mfma_f32_32x32x16_bf16(a, b, acc, 0, 0, 0);
    }

    // ---- epilogue 1: H = relu(acc + b1) -> LDS, (row&31)<<4 swizzle ----
    char* sHb = (char*)sH;
    {
        const int col = w * 32 + cn;
        const float bv = bias1[col];
#pragma unroll
        for (int r = 0; r < 16; ++r) {
            const int rowl = (r & 3) + 8 * (r >> 2) + 4 * p;   // 0..31
            float v = acc[r] + bv;
            v = v > 0.0f ? v : 0.0f;
            int ba = rowl * (HID * 2) + col * 2;
            ba ^= (rowl & 31) << 4;
            *(bf16*)(sHb + ba) = (bf16)v;
        }
    }
    __syncthreads();

    // ---- phase 2: acc = H @ W2 (A from LDS, barrier-free) ----
#pragma unroll
    for (int r = 0; r < 16; ++r) acc[r] = 0.0f;

    const int hrow = cn;
    const int hswz = (hrow & 31) << 4;
    constexpr int T2 = HID / 16;
#pragma unroll
    for (int t = 0; t < T2; ++t) {
        const int kb = (t * 16 + p * 8) * 2;
        bf16x8 a = *(const bf16x8*)(sHb + ((hrow * (HID * 2) + kb) ^ hswz));
        bf16x8 b = *(const bf16x8*)(Wf2 + ((((t >> 1) * 16 + w * 2 + (t & 1)) * 64) + lane) * 8);
        acc = __builtin_amdgcn_mfma_f32_32x32x16_bf16(a, b, acc, 0, 0, 0);
    }

    // ---- epilogue 2: bias2 + relu + store + slotted colsum ----
    {
        const int col = w * 32 + cn;
        const float bv = bias2[col];
        float part = 0.0f;
#pragma unroll
        for (int r = 0; r < 16; ++r) {
            int rl = (r & 3) + 8 * (r >> 2) + 4 * p;
            int mo = m_base + rl;
            if (mo < M) {
                float v = acc[r] + bv;
                v = v > 0.0f ? v : 0.0f;
                if constexpr (OCHUNK == 0)
                    out_bf[(size_t)mo * HID + col] = (bf16)v;
                else
                    out_bf[((size_t)w * N_NODES + mo) * OCHUNK + cn] = (bf16)v;
                part += v;
            }
        }
        if (colsum8) {
            part += __shfl_xor(part, 32, 64);   // combine the two p-halves
            if (p == 0) atomicAdd(&colsum8[(blockIdx.x & 7) * HID + col], part);
        }
    }
}

// ---------------------------------------------------------------------------
// Graph head: three GEMVs + sum + final GEMV, single block of 256 threads.
// All colsums are 8-slotted.
__global__ void graph_head(const float* __restrict__ cs0_8,
                           const float* __restrict__ cs1_8,
                           const float* __restrict__ cs2_8,
                           const float* __restrict__ g0w, const float* __restrict__ g0b,
                           const float* __restrict__ g1w, const float* __restrict__ g1b,
                           const float* __restrict__ g2w, const float* __restrict__ g2b,
                           const float* __restrict__ glw, const float* __restrict__ glb,
                           float* __restrict__ gvec)
{
    __shared__ float v0[IN_DIM], v1[HID], v2[HID], gs[HID];
    int t = threadIdx.x;
    if (t < IN_DIM) {
        float s = 0.0f;
#pragma unroll
        for (int i = 0; i < 8; ++i) s += cs0_8[i * KPAD1 + t];
        v0[t] = s;
    }
    {
        float s1 = 0.0f, s2 = 0.0f;
#pragma unroll
        for (int i = 0; i < 8; ++i) {
            s1 += cs1_8[i * HID + t];
            s2 += cs2_8[i * HID + t];
        }
        v1[t] = s1;
        v2[t] = s2;
    }
    __syncthreads();

    float a0 = 0.0f, a1 = 0.0f, a2 = 0.0f;
    for (int k = 0; k < IN_DIM; ++k) a0 += v0[k] * g0w[k * HID + t];
    for (int k = 0; k < HID; ++k) {
        a1 += v1[k] * g1w[k * HID + t];
        a2 += v2[k] * g2w[k * HID + t];
    }
    float e0 = fmaxf(a0 + g0b[t], 0.0f);
    float e1 = fmaxf(a1 + g1b[t], 0.0f);
    float e2 = fmaxf(a2 + g2b[t], 0.0f);
    gs[t] = e0 + e1 + e2;
    __syncthreads();

    float a3 = 0.0f;
    for (int k = 0; k < HID; ++k) a3 += gs[k] * glw[k * HID + t];
    gvec[t] = fmaxf(a3 + glb[t], 0.0f);
}

// ---------------------------------------------------------------------------
// out[n,c] = node2[n,c](bf16) + gvec[c] (f32 out); 4 elements per thread.
__global__ void final_add(const bf16* __restrict__ node2,
                          const float* __restrict__ gvec,
                          float* __restrict__ out)
{
    int idx = blockIdx.x * blockDim.x + threadIdx.x;
    size_t base = (size_t)idx * 4;
    int c = (int)(base & (HID - 1));
    bf16x4 v = *(const bf16x4*)(node2 + base);
    f32x4 g = *(const f32x4*)(gvec + c);
    f32x4 o;
#pragma unroll
    for (int j = 0; j < 4; ++j) o[j] = (float)v[j] + g[j];
    *(f32x4*)(out + base) = o;
}

// ---------------------------------------------------------------------------
extern "C" void kernel_launch(void* const* d_in, const int* in_sizes, int n_in,
                              void* d_out, int out_size, void* d_ws, size_t ws_size,
                              hipStream_t stream)
{
    const float* feat = (const float*)d_in[0];
    const int*   ei   = (const int*)d_in[1];
    const int*   src  = ei;
    const int*   dst  = ei + N_EDGES;
    const float* g0w = (const float*)d_in[2],  *g0b = (const float*)d_in[3];
    const float* g1w = (const float*)d_in[4],  *g1b = (const float*)d_in[5];
    const float* g2w = (const float*)d_in[6],  *g2b = (const float*)d_in[7];
    const float* glw = (const float*)d_in[8],  *glb = (const float*)d_in[9];
    const float* m1aw = (const float*)d_in[10], *m1ab = (const float*)d_in[11];
    const float* m1bw = (const float*)d_in[12], *m1bb = (const float*)d_in[13];
    const float* m2aw = (const float*)d_in[14], *m2ab = (const float*)d_in[15];
    const float* m2bw = (const float*)d_in[16], *m2bb = (const float*)d_in[17];
    float* out = (float*)d_out;

    char* ws = (char*)d_ws;
    size_t off = 0;
    auto alloc = [&](size_t bytes) -> void* {
        void* p = ws + off;
        off += (bytes + 255) & ~(size_t)255;
        return p;
    };
    bf16*  featbf = (bf16*)alloc((size_t)N_NODES * KPAD1 * 2);   // tiled [8][N][24]
    bf16*  xsum  = (bf16*) alloc((size_t)N_NODES * KPAD1 * 2);   // tiled [8][N][24]
    bf16*  y2    = (bf16*) alloc((size_t)N_NODES * HID * 2);     // tiled [8][N][32]
    bf16*  node2 = (bf16*) alloc((size_t)N_NODES * HID * 2);     // linear
    bf16*  node1 = (bf16*) alloc((size_t)N_NODES * HID * 2);     // tiled [8][N][32]
    bf16*  Wf1   = (bf16*) alloc((size_t)HID * KPAD1 * 2);       // frag-major
    bf16*  Wf2   = (bf16*) alloc((size_t)HID * HID * 2);
    bf16*  Wf3   = (bf16*) alloc((size_t)HID * HID * 2);
    bf16*  Wf4   = (bf16*) alloc((size_t)HID * HID * 2);
    int*   deg     = (int*)alloc((size_t)N_NODES * 4);
    int*   rowptr  = (int*)alloc((size_t)(N_NODES + 1) * 4);
    int*   cursor  = (int*)alloc((size_t)N_NODES * 4);
    int*   csr_src = (int*)alloc((size_t)N_EDGES * 4);
    int*   bsum    = (int*)alloc(256 * 4);
    int*   gsum    = (int*)alloc(256 * 4);
    float* csums   = (float*)alloc((8 * KPAD1 + 8 * HID + 8 * HID + HID) * 4);
    float* colsum0_8 = csums;                          // 8 x 192 slots
    float* colsum1_8 = csums + 8 * KPAD1;              // 8 x 256 slots
    float* colsum2_8 = csums + 8 * KPAD1 + 8 * HID;    // 8 x 256 slots
    float* gvec      = csums + 8 * KPAD1 + 16 * HID;   // 256

    hipMemsetAsync(csums, 0, (8 * KPAD1 + 16 * HID) * 4, stream);
    hipMemsetAsync(deg, 0, (size_t)N_NODES * 4, stream);

    // all independent preprocessing in one launch
    prep_all<<<WTB + FPB + DGB, 256, 0, stream>>>(
        m1aw, m1bw, m2aw, m2bw, Wf1, Wf2, Wf3, Wf4,
        feat, featbf, colsum0_8, dst, deg);

    // CSR scan chain
    block_degsum<<<NB, 256, 0, stream>>>(deg, bsum);
    scan_bsum<<<1, 256, 0, stream>>>(bsum, gsum);
    block_scan_write<<<NB, 256, 0, stream>>>(deg, gsum, rowptr, cursor);
    csr_fill<<<N_EDGES / 256, 256, 0, stream>>>(src, dst, cursor, csr_src);

    const int gtiles = (N_NODES + 15) / 16;   // 4 nodes/wave x 4 waves
    // xsum = bf16(feat + gather(feat)) — tiled, XCD-pinned, register-idx
    gather_v5<24, 3><<<gtiles * 8, 256, 0, stream>>>(featbf, rowptr, csr_src, xsum);

    const int gblocks = (N_NODES + 31) / 32;   // 1563
    // node1 = relu(relu(xsum@W1+b1)@W2+b2), colsum1 fused   (A tiled24 -> tiled32 out)
    gemm_mlp32<KPAD1, 24, 32><<<gblocks, 512, 0, stream>>>(
        xsum, Wf1, m1ab, Wf2, m1bb, node1, colsum1_8, N_NODES);
    // y2 = bf16(node1 + gather(node1)) — tiled, XCD-pinned, register-idx
    gather_v5<32, 4><<<gtiles * 8, 256, 0, stream>>>(node1, rowptr, csr_src, y2);
    // node2 = relu(relu(y2@W3+b3)@W4+b4), colsum2 fused     (A tiled32 -> linear out)
    gemm_mlp32<HID, 32, 0><<<gblocks, 512, 0, stream>>>(
        y2, Wf3, m2ab, Wf4, m2bb, node2, colsum2_8, N_NODES);
    // graph head -> gvec = g_last
    graph_head<<<1, 256, 0, stream>>>(colsum0_8, colsum1_8, colsum2_8,
                                      g0w, g0b, g1w, g1b, g2w, g2b, glw, glb, gvec);
    // out = node2 + gvec
    final_add<<<((size_t)N_NODES * HID / 4 + 255) / 256, 256, 0, stream>>>(node2, gvec, out);
    (void)in_sizes; (void)n_in; (void)out_size; (void)ws_size;
}

// Round 10
// 425.535 us; speedup vs baseline: 1.2755x; 1.0700x over previous
//
#include <hip/hip_runtime.h>

#define N_NODES 50000
#define N_EDGES 800000
#define IN_DIM  162
#define HID     256
#define KPAD1   192   // IN_DIM padded to multiple of 32
#define NB      ((N_NODES + 255) / 256)   // 196 scan blocks

typedef __bf16 bf16;
typedef __bf16 bf16x8 __attribute__((ext_vector_type(8)));
typedef __bf16 bf16x4 __attribute__((ext_vector_type(4)));
typedef float  f32x4  __attribute__((ext_vector_type(4)));
typedef float  f32x8  __attribute__((ext_vector_type(8)));
typedef float  f32x16 __attribute__((ext_vector_type(16)));

// ---------------------------------------------------------------------------
// Frag-major weight pack: Wf element E holds the MFMA B-frag element
//   fb = jg*2+kk, E = ((ks*16 + fb)*64 + lane)*8 + e
//   -> W[k][n], n = jg*32 + (lane&31), k = ks*32 + kk*16 + (lane>>5)*8 + e
__device__ __forceinline__ void wf_one(const float* W, bf16* Wf, int K, int E)
{
    int e    = E & 7;
    int lane = (E >> 3) & 63;
    int fb   = (E >> 9) & 15;
    int ks   = E >> 13;
    int n = (fb >> 1) * 32 + (lane & 31);
    int k = ks * 32 + (fb & 1) * 16 + (lane >> 5) * 8 + e;
    Wf[E] = (k < K) ? (bf16)W[(size_t)k * HID + n] : (bf16)0.0f;
}

// ---------------------------------------------------------------------------
// prep_all v3: one launch, partitioned by block.
//   [0, WTB)       : frag-major weight packs (4 matrices)
//   [WTB, +FPB)    : feat prep: single coalesced read, REGISTER colsum
//                    partials (no LDS atomics — r9's 150K bank conflicts),
//                    LDS-staged bf16 tile, coalesced group-major writes
//   [.., +DGB)     : degree histogram
#define WTB  ((HID * KPAD1 + 3 * HID * HID + 255) / 256)          // 960
#define FPB  ((N_NODES + 63) / 64)                                // 782
#define DGB  (N_EDGES / 256)                                      // 3125

__global__ void prep_all(const float* __restrict__ m1aw, const float* __restrict__ m1bw,
                         const float* __restrict__ m2aw, const float* __restrict__ m2bw,
                         bf16* __restrict__ Wf1, bf16* __restrict__ Wf2,
                         bf16* __restrict__ Wf3, bf16* __restrict__ Wf4,
                         const float* __restrict__ feat, bf16* __restrict__ featbf,
                         float* __restrict__ colsum8,
                         const int* __restrict__ dst, int* __restrict__ deg)
{
    __shared__ bf16  tile[64][208];   // padded rows (416B stride)
    __shared__ float pcs[4][KPAD1];   // per-rowgroup colsum partials

    const int b   = blockIdx.x;
    const int tid = threadIdx.x;

    if (b < WTB) {
        const int R1 = HID * KPAD1;
        const int R2 = HID * HID;
        int idx = b * 256 + tid;
        if (idx < R1)                 wf_one(m1aw, Wf1, IN_DIM, idx);
        else if (idx < R1 + R2)       wf_one(m1bw, Wf2, HID, idx - R1);
        else if (idx < R1 + 2 * R2)   wf_one(m2aw, Wf3, HID, idx - R1 - R2);
        else if (idx < R1 + 3 * R2)   wf_one(m2bw, Wf4, HID, idx - R1 - 2 * R2);
        return;
    }
    if (b < WTB + FPB) {
        const int fp = b - WTB;
        const int r0 = fp * 64;

        // phase A: thread t<192 owns column-quad ch=t%48 for row-group rg=t/48
        // (16 rows each). feat read ONCE, coalesced (48-thread runs per row);
        // colsum partials accumulate in REGISTERS (f32, same numerics as the
        // verified colsum path). bf16 tile staged with plain LDS stores.
        if (tid < 192) {
            const int ch = tid % 48;
            const int rg = tid / 48;
            const int c4 = ch * 4;
            float a0 = 0.0f, a1 = 0.0f, a2 = 0.0f, a3 = 0.0f;
#pragma unroll 4
            for (int k = 0; k < 16; ++k) {
                const int rl = rg * 16 + k;
                const int r  = r0 + rl;
                bf16x4 o;
                if (r < N_NODES) {
                    const float* fr = feat + (size_t)r * IN_DIM;
                    float f0 = (c4 + 0 < IN_DIM) ? fr[c4 + 0] : 0.0f;
                    float f1 = (c4 + 1 < IN_DIM) ? fr[c4 + 1] : 0.0f;
                    float f2 = (c4 + 2 < IN_DIM) ? fr[c4 + 2] : 0.0f;
                    float f3 = (c4 + 3 < IN_DIM) ? fr[c4 + 3] : 0.0f;
                    a0 += f0; a1 += f1; a2 += f2; a3 += f3;
                    o[0] = (bf16)f0; o[1] = (bf16)f1; o[2] = (bf16)f2; o[3] = (bf16)f3;
                } else {
#pragma unroll
                    for (int j = 0; j < 4; ++j) o[j] = (bf16)0.0f;
                }
                *(bf16x4*)(&tile[rl][c4]) = o;
            }
            pcs[rg][c4 + 0] = a0;
            pcs[rg][c4 + 1] = a1;
            pcs[rg][c4 + 2] = a2;
            pcs[rg][c4 + 3] = a3;
        }
        __syncthreads();

        // phase B: group-major coalesced writes: 8 groups x 64 rows x 24 cols
        // = 1536 x 16B chunks, contiguous per group.
#pragma unroll
        for (int i = 0; i < 6; ++i) {
            int m  = i * 256 + tid;           // [0, 1536)
            int g  = m / 192;                 // 192 chunks per group
            int wg = m - g * 192;
            int eo = wg * 8;                  // elem offset in 64x24 group block
            int rl = eo / 24;
            int cc = eo - rl * 24;
            int r  = r0 + rl;
            if (r < N_NODES) {
                bf16x8 o = *(const bf16x8*)(&tile[rl][g * 24 + cc]);
                *(bf16x8*)(featbf + ((size_t)g * N_NODES + r0) * 24 + (size_t)rl * 24 + cc) = o;
            }
        }

        // phase C: combine 4 row-group partials, one global atomic per column
        if (tid < IN_DIM) {
            float s = pcs[0][tid] + pcs[1][tid] + pcs[2][tid] + pcs[3][tid];
            atomicAdd(&colsum8[(fp & 7) * KPAD1 + tid], s);
        }
        return;
    }
    {
        int e = (b - WTB - FPB) * 256 + tid;
        atomicAdd(&deg[dst[e]], 1);
    }
}

// ---------------------------------------------------------------------------
// CSR build (scan chain).
__global__ void block_degsum(const int* __restrict__ deg, int* __restrict__ bsum)
{
    __shared__ int s[256];
    int t = threadIdx.x;
    int idx = blockIdx.x * 256 + t;
    int v = (idx < N_NODES) ? deg[idx] : 0;
    s[t] = v;
    __syncthreads();
    for (int off = 128; off > 0; off >>= 1) {
        if (t < off) s[t] += s[t + off];
        __syncthreads();
    }
    if (t == 0) bsum[blockIdx.x] = s[0];
}

__global__ void scan_bsum(const int* __restrict__ bsum, int* __restrict__ gsum)
{
    __shared__ int s[256];
    int t = threadIdx.x;
    int v = (t < NB) ? bsum[t] : 0;
    s[t] = v;
    __syncthreads();
    for (int off = 1; off < 256; off <<= 1) {
        int u = (t >= off) ? s[t - off] : 0;
        __syncthreads();
        s[t] += u;
        __syncthreads();
    }
    gsum[t] = s[t] - v;
}

__global__ void block_scan_write(const int* __restrict__ deg, const int* __restrict__ gsum,
                                 int* __restrict__ rowptr, int* __restrict__ cursor)
{
    __shared__ int s[256];
    int t = threadIdx.x;
    int idx = blockIdx.x * 256 + t;
    int v = (idx < N_NODES) ? deg[idx] : 0;
    s[t] = v;
    __syncthreads();
    for (int off = 1; off < 256; off <<= 1) {
        int u = (t >= off) ? s[t - off] : 0;
        __syncthreads();
        s[t] += u;
        __syncthreads();
    }
    int excl = s[t] - v + gsum[blockIdx.x];
    if (idx < N_NODES) {
        rowptr[idx] = excl;
        cursor[idx] = excl;
    }
    if (idx == 0) rowptr[N_NODES] = N_EDGES;
}

__global__ void csr_fill(const int* __restrict__ src, const int* __restrict__ dst,
                         int* __restrict__ cursor, int* __restrict__ csr_src)
{
    int e = blockIdx.x * blockDim.x + threadIdx.x;
    int p = atomicAdd(&cursor[dst[e]], 1);
    csr_src[p] = src[e];
}

// ---------------------------------------------------------------------------
// Gather v5: tiled [8][N][CHUNK] input/output, XCD-pinned groups, in-register
// index list, masked unrolled row-load blocks.
template<int CHUNK, int NACT>
__launch_bounds__(256)
__global__ void gather_v5(const bf16* __restrict__ xin,
                          const int* __restrict__ rowptr,
                          const int* __restrict__ csr_src,
                          bf16* __restrict__ xout)
{
    const int g    = blockIdx.x & 7;
    const int tile = blockIdx.x >> 3;
    const int wv   = threadIdx.x >> 6;
    const int lane = threadIdx.x & 63;
    const int q    = lane >> 4;          // node within wave 0..3
    const int j    = lane & 15;          // idx slot
    const int e    = j >> 2;             // stripe 0..3
    const int c4   = j & 3;              // 16B chunk
    const int n    = tile * 16 + wv * 4 + q;
    const bool valid = (n < N_NODES);
    const bool act   = (c4 < NACT);
    const int  ce    = c4 * 8;
    const bf16* base = xin + (size_t)g * N_NODES * CHUNK;

    int r0 = 0, deg = 0;
    if (valid) {
        r0  = rowptr[n];
        deg = rowptr[n + 1] - r0;
    }

    int a0 = r0 + j;        if (a0 > N_EDGES - 1) a0 = N_EDGES - 1;
    int a1 = r0 + 16 + j;   if (a1 > N_EDGES - 1) a1 = N_EDGES - 1;
    const int i0 = csr_src[a0];
    const int i1 = csr_src[a1];

    f32x8 acc;
#pragma unroll
    for (int t = 0; t < 8; ++t) acc[t] = 0.0f;
    if (valid && e == 0 && act) {
        bf16x8 t0 = *(const bf16x8*)(base + (size_t)n * CHUNK + ce);
#pragma unroll
        for (int t = 0; t < 8; ++t) acc[t] = (float)t0[t];
    }

    const int lb = lane & ~3;

    // ---- block 1: positions 4e + k ----
    {
        const int s0 = __shfl(i0, lb + 0, 64);
        const int s1 = __shfl(i0, lb + 1, 64);
        const int s2 = __shfl(i0, lb + 2, 64);
        const int s3 = __shfl(i0, lb + 3, 64);
        const int p0 = 4 * e;
        if (act) {
            bf16x8 u0 = *(const bf16x8*)(base + (size_t)s0 * CHUNK + ce);
            bf16x8 u1 = *(const bf16x8*)(base + (size_t)s1 * CHUNK + ce);
            bf16x8 u2 = *(const bf16x8*)(base + (size_t)s2 * CHUNK + ce);
            bf16x8 u3 = *(const bf16x8*)(base + (size_t)s3 * CHUNK + ce);
            if (p0 + 0 < deg) {
#pragma unroll
                for (int t = 0; t < 8; ++t) acc[t] += (float)u0[t];
            }
            if (p0 + 1 < deg) {
#pragma unroll
                for (int t = 0; t < 8; ++t) acc[t] += (float)u1[t];
            }
            if (p0 + 2 < deg) {
#pragma unroll
                for (int t = 0; t < 8; ++t) acc[t] += (float)u2[t];
            }
            if (p0 + 3 < deg) {
#pragma unroll
                for (int t = 0; t < 8; ++t) acc[t] += (float)u3[t];
            }
        }
    }

    // ---- block 2: positions 16 + 4e + k, stripe-gated ----
    {
        const int s0 = __shfl(i1, lb + 0, 64);
        const int s1 = __shfl(i1, lb + 1, 64);
        const int s2 = __shfl(i1, lb + 2, 64);
        const int s3 = __shfl(i1, lb + 3, 64);
        const int p0 = 16 + 4 * e;
        if (act && p0 < deg) {
            bf16x8 u0 = *(const bf16x8*)(base + (size_t)s0 * CHUNK + ce);
            bf16x8 u1 = *(const bf16x8*)(base + (size_t)s1 * CHUNK + ce);
            bf16x8 u2 = *(const bf16x8*)(base + (size_t)s2 * CHUNK + ce);
            bf16x8 u3 = *(const bf16x8*)(base + (size_t)s3 * CHUNK + ce);
            {
#pragma unroll
                for (int t = 0; t < 8; ++t) acc[t] += (float)u0[t];
            }
            if (p0 + 1 < deg) {
#pragma unroll
                for (int t = 0; t < 8; ++t) acc[t] += (float)u1[t];
            }
            if (p0 + 2 < deg) {
#pragma unroll
                for (int t = 0; t < 8; ++t) acc[t] += (float)u2[t];
            }
            if (p0 + 3 < deg) {
#pragma unroll
                for (int t = 0; t < 8; ++t) acc[t] += (float)u3[t];
            }
        }
    }

    // ---- rare tail: deg > 32 ----
    for (int p = 32 + e; p < deg; p += 4) {
        const int s = csr_src[r0 + p];
        if (act) {
            bf16x8 u = *(const bf16x8*)(base + (size_t)s * CHUNK + ce);
#pragma unroll
            for (int t = 0; t < 8; ++t) acc[t] += (float)u[t];
        }
    }

#pragma unroll
    for (int t = 0; t < 8; ++t) {
        acc[t] += __shfl_xor(acc[t], 4, 64);
        acc[t] += __shfl_xor(acc[t], 8, 64);
    }

    if (valid && e == 0 && act) {
        bf16x8 o;
#pragma unroll
        for (int t = 0; t < 8; ++t) o[t] = (bf16)acc[t];
        __builtin_nontemporal_store(o,
            (bf16x8*)(xout + ((size_t)g * N_NODES + n) * CHUNK + ce));
    }
}

// ---------------------------------------------------------------------------
// Fused GIN MLP "gemm_mlp32": out = relu(relu(X@W1+b1)@W2+b2).
// 32-row blocks, 8 waves; wave w owns cols [w*32, w*32+32) over all 32 rows
// -> 32x32 per wave, acc = 1 f32x16. Grid = 1563 blocks = 12512 waves —
// maximize TLP for this latency-bound regime (r7 vs r8 A/B evidence).
// B-frags coalesced from frag-major Wf (L2-resident); no K-loop barriers.
// H in LDS (16KB), (row&31)<<4 XOR swizzle (bank-conflict 0 measured r7/r8).
// colsum (nullable) is 8-slotted [8][HID]; slot = blockIdx&7.
// ACHUNK: 0 = X linear [M][KPAD]; else X tiled [KPAD/ACHUNK][N_NODES][ACHUNK].
// OCHUNK: 0 = out linear [M][HID]; else out tiled [HID/32][N_NODES][32].
template<int KPAD, int ACHUNK, int OCHUNK>
__launch_bounds__(512)
__global__ void gemm_mlp32(const bf16* __restrict__ X,
                           const bf16* __restrict__ Wf1,
                           const float* __restrict__ bias1,
                           const bf16* __restrict__ Wf2,
                           const float* __restrict__ bias2,
                           bf16* __restrict__ out_bf,
                           float* __restrict__ colsum8,  // [8][HID] or null
                           int M)
{
    __shared__ __align__(128) bf16 sH[32 * HID];   // 16 KB

    const int tid  = threadIdx.x;
    const int w    = tid >> 6;     // col group 0..7
    const int lane = tid & 63;
    const int p    = lane >> 5;
    const int cn   = lane & 31;
    const int m_base = blockIdx.x * 32;

    int arow = m_base + cn;
    if (arow >= M) arow = M - 1;   // clamp (stores guarded)

    f32x16 acc;
#pragma unroll
    for (int r = 0; r < 16; ++r) acc[r] = 0.0f;

    // ---- phase 1: acc = X @ W1 (barrier-free) ----
    constexpr int T1 = KPAD / 16;
#pragma unroll
    for (int t = 0; t < T1; ++t) {
        bf16x8 a;
        {
            const int e = t * 16 + p * 8;
            if constexpr (ACHUNK == 0) {
                a = *(const bf16x8*)(X + (size_t)arow * KPAD + e);
            } else {
                const int gch = e / ACHUNK;
                const int off = e - gch * ACHUNK;
                a = *(const bf16x8*)(X + ((size_t)gch * N_NODES + arow) * ACHUNK + off);
            }
        }
        bf16x8 b = *(const bf16x8*)(Wf1 + ((((t >> 1) * 16 + w * 2 + (t & 1)) * 64) + lane) * 8);
        acc = __builtin_amdgcn_mfma_f32_32x32x16_bf16(a, b, acc, 0, 0, 0);
    }

    // ---- epilogue 1: H = relu(acc + b1) -> LDS, (row&31)<<4 swizzle ----
    char* sHb = (char*)sH;
    {
        const int col = w * 32 + cn;
        const float bv = bias1[col];
#pragma unroll
        for (int r = 0; r < 16; ++r) {
            const int rowl = (r & 3) + 8 * (r >> 2) + 4 * p;   // 0..31
            float v = acc[r] + bv;
            v = v > 0.0f ? v : 0.0f;
            int ba = rowl * (HID * 2) + col * 2;
            ba ^= (rowl & 31) << 4;
            *(bf16*)(sHb + ba) = (bf16)v;
        }
    }
    __syncthreads();

    // ---- phase 2: acc = H @ W2 (A from LDS, barrier-free) ----
#pragma unroll
    for (int r = 0; r < 16; ++r) acc[r] = 0.0f;

    const int hrow = cn;
    const int hswz = (hrow & 31) << 4;
    constexpr int T2 = HID / 16;
#pragma unroll
    for (int t = 0; t < T2; ++t) {
        const int kb = (t * 16 + p * 8) * 2;
        bf16x8 a = *(const bf16x8*)(sHb + ((hrow * (HID * 2) + kb) ^ hswz));
        bf16x8 b = *(const bf16x8*)(Wf2 + ((((t >> 1) * 16 + w * 2 + (t & 1)) * 64) + lane) * 8);
        acc = __builtin_amdgcn_mfma_f32_32x32x16_bf16(a, b, acc, 0, 0, 0);
    }

    // ---- epilogue 2: bias2 + relu + store + slotted colsum ----
    {
        const int col = w * 32 + cn;
        const float bv = bias2[col];
        float part = 0.0f;
#pragma unroll
        for (int r = 0; r < 16; ++r) {
            int rl = (r & 3) + 8 * (r >> 2) + 4 * p;
            int mo = m_base + rl;
            if (mo < M) {
                float v = acc[r] + bv;
                v = v > 0.0f ? v : 0.0f;
                if constexpr (OCHUNK == 0)
                    out_bf[(size_t)mo * HID + col] = (bf16)v;
                else
                    out_bf[((size_t)w * N_NODES + mo) * OCHUNK + cn] = (bf16)v;
                part += v;
            }
        }
        if (colsum8) {
            part += __shfl_xor(part, 32, 64);   // combine the two p-halves
            if (p == 0) atomicAdd(&colsum8[(blockIdx.x & 7) * HID + col], part);
        }
    }
}

// ---------------------------------------------------------------------------
// Graph head: three GEMVs + sum + final GEMV, single block of 256 threads.
// All colsums are 8-slotted.
__global__ void graph_head(const float* __restrict__ cs0_8,
                           const float* __restrict__ cs1_8,
                           const float* __restrict__ cs2_8,
                           const float* __restrict__ g0w, const float* __restrict__ g0b,
                           const float* __restrict__ g1w, const float* __restrict__ g1b,
                           const float* __restrict__ g2w, const float* __restrict__ g2b,
                           const float* __restrict__ glw, const float* __restrict__ glb,
                           float* __restrict__ gvec)
{
    __shared__ float v0[IN_DIM], v1[HID], v2[HID], gs[HID];
    int t = threadIdx.x;
    if (t < IN_DIM) {
        float s = 0.0f;
#pragma unroll
        for (int i = 0; i < 8; ++i) s += cs0_8[i * KPAD1 + t];
        v0[t] = s;
    }
    {
        float s1 = 0.0f, s2 = 0.0f;
#pragma unroll
        for (int i = 0; i < 8; ++i) {
            s1 += cs1_8[i * HID + t];
            s2 += cs2_8[i * HID + t];
        }
        v1[t] = s1;
        v2[t] = s2;
    }
    __syncthreads();

    float a0 = 0.0f, a1 = 0.0f, a2 = 0.0f;
    for (int k = 0; k < IN_DIM; ++k) a0 += v0[k] * g0w[k * HID + t];
    for (int k = 0; k < HID; ++k) {
        a1 += v1[k] * g1w[k * HID + t];
        a2 += v2[k] * g2w[k * HID + t];
    }
    float e0 = fmaxf(a0 + g0b[t], 0.0f);
    float e1 = fmaxf(a1 + g1b[t], 0.0f);
    float e2 = fmaxf(a2 + g2b[t], 0.0f);
    gs[t] = e0 + e1 + e2;
    __syncthreads();

    float a3 = 0.0f;
    for (int k = 0; k < HID; ++k) a3 += gs[k] * glw[k * HID + t];
    gvec[t] = fmaxf(a3 + glb[t], 0.0f);
}

// ---------------------------------------------------------------------------
// out[n,c] = node2[n,c](bf16) + gvec[c] (f32 out); 4 elements per thread.
__global__ void final_add(const bf16* __restrict__ node2,
                          const float* __restrict__ gvec,
                          float* __restrict__ out)
{
    int idx = blockIdx.x * blockDim.x + threadIdx.x;
    size_t base = (size_t)idx * 4;
    int c = (int)(base & (HID - 1));
    bf16x4 v = *(const bf16x4*)(node2 + base);
    f32x4 g = *(const f32x4*)(gvec + c);
    f32x4 o;
#pragma unroll
    for (int j = 0; j < 4; ++j) o[j] = (float)v[j] + g[j];
    *(f32x4*)(out + base) = o;
}

// ---------------------------------------------------------------------------
extern "C" void kernel_launch(void* const* d_in, const int* in_sizes, int n_in,
                              void* d_out, int out_size, void* d_ws, size_t ws_size,
                              hipStream_t stream)
{
    const float* feat = (const float*)d_in[0];
    const int*   ei   = (const int*)d_in[1];
    const int*   src  = ei;
    const int*   dst  = ei + N_EDGES;
    const float* g0w = (const float*)d_in[2],  *g0b = (const float*)d_in[3];
    const float* g1w = (const float*)d_in[4],  *g1b = (const float*)d_in[5];
    const float* g2w = (const float*)d_in[6],  *g2b = (const float*)d_in[7];
    const float* glw = (const float*)d_in[8],  *glb = (const float*)d_in[9];
    const float* m1aw = (const float*)d_in[10], *m1ab = (const float*)d_in[11];
    const float* m1bw = (const float*)d_in[12], *m1bb = (const float*)d_in[13];
    const float* m2aw = (const float*)d_in[14], *m2ab = (const float*)d_in[15];
    const float* m2bw = (const float*)d_in[16], *m2bb = (const float*)d_in[17];
    float* out = (float*)d_out;

    char* ws = (char*)d_ws;
    size_t off = 0;
    auto alloc = [&](size_t bytes) -> void* {
        void* p = ws + off;
        off += (bytes + 255) & ~(size_t)255;
        return p;
    };
    bf16*  featbf = (bf16*)alloc((size_t)N_NODES * KPAD1 * 2);   // tiled [8][N][24]
    bf16*  xsum  = (bf16*) alloc((size_t)N_NODES * KPAD1 * 2);   // tiled [8][N][24]
    bf16*  y2    = (bf16*) alloc((size_t)N_NODES * HID * 2);     // tiled [8][N][32]
    bf16*  node2 = (bf16*) alloc((size_t)N_NODES * HID * 2);     // linear
    bf16*  node1 = (bf16*) alloc((size_t)N_NODES * HID * 2);     // tiled [8][N][32]
    bf16*  Wf1   = (bf16*) alloc((size_t)HID * KPAD1 * 2);       // frag-major
    bf16*  Wf2   = (bf16*) alloc((size_t)HID * HID * 2);
    bf16*  Wf3   = (bf16*) alloc((size_t)HID * HID * 2);
    bf16*  Wf4   = (bf16*) alloc((size_t)HID * HID * 2);
    int*   deg     = (int*)alloc((size_t)N_NODES * 4);
    int*   rowptr  = (int*)alloc((size_t)(N_NODES + 1) * 4);
    int*   cursor  = (int*)alloc((size_t)N_NODES * 4);
    int*   csr_src = (int*)alloc((size_t)N_EDGES * 4);
    int*   bsum    = (int*)alloc(256 * 4);
    int*   gsum    = (int*)alloc(256 * 4);
    float* csums   = (float*)alloc((8 * KPAD1 + 8 * HID + 8 * HID + HID) * 4);
    float* colsum0_8 = csums;                          // 8 x 192 slots
    float* colsum1_8 = csums + 8 * KPAD1;              // 8 x 256 slots
    float* colsum2_8 = csums + 8 * KPAD1 + 8 * HID;    // 8 x 256 slots
    float* gvec      = csums + 8 * KPAD1 + 16 * HID;   // 256

    hipMemsetAsync(csums, 0, (8 * KPAD1 + 16 * HID) * 4, stream);
    hipMemsetAsync(deg, 0, (size_t)N_NODES * 4, stream);

    // all independent preprocessing in one launch
    prep_all<<<WTB + FPB + DGB, 256, 0, stream>>>(
        m1aw, m1bw, m2aw, m2bw, Wf1, Wf2, Wf3, Wf4,
        feat, featbf, colsum0_8, dst, deg);

    // CSR scan chain
    block_degsum<<<NB, 256, 0, stream>>>(deg, bsum);
    scan_bsum<<<1, 256, 0, stream>>>(bsum, gsum);
    block_scan_write<<<NB, 256, 0, stream>>>(deg, gsum, rowptr, cursor);
    csr_fill<<<N_EDGES / 256, 256, 0, stream>>>(src, dst, cursor, csr_src);

    const int gtiles = (N_NODES + 15) / 16;   // 4 nodes/wave x 4 waves
    // xsum = bf16(feat + gather(feat)) — tiled, XCD-pinned, register-idx
    gather_v5<24, 3><<<gtiles * 8, 256, 0, stream>>>(featbf, rowptr, csr_src, xsum);

    const int gblocks = (N_NODES + 31) / 32;   // 1563
    // node1 = relu(relu(xsum@W1+b1)@W2+b2), colsum1 fused   (A tiled24 -> tiled32 out)
    gemm_mlp32<KPAD1, 24, 32><<<gblocks, 512, 0, stream>>>(
        xsum, Wf1, m1ab, Wf2, m1bb, node1, colsum1_8, N_NODES);
    // y2 = bf16(node1 + gather(node1)) — tiled, XCD-pinned, register-idx
    gather_v5<32, 4><<<gtiles * 8, 256, 0, stream>>>(node1, rowptr, csr_src, y2);
    // node2 = relu(relu(y2@W3+b3)@W4+b4), colsum2 fused     (A tiled32 -> linear out)
    gemm_mlp32<HID, 32, 0><<<gblocks, 512, 0, stream>>>(
        y2, Wf3, m2ab, Wf4, m2bb, node2, colsum2_8, N_NODES);
    // graph head -> gvec = g_last
    graph_head<<<1, 256, 0, stream>>>(colsum0_8, colsum1_8, colsum2_8,
                                      g0w, g0b, g1w, g1b, g2w, g2b, glw, glb, gvec);
    // out = node2 + gvec
    final_add<<<((size_t)N_NODES * HID / 4 + 255) / 256, 256, 0, stream>>>(node2, gvec, out);
    (void)in_sizes; (void)n_in; (void)out_size; (void)ws_size;
}

// Round 11
// 419.322 us; speedup vs baseline: 1.2944x; 1.0148x over previous
//
#include <hip/hip_runtime.h>

#define N_NODES 50000
#define N_EDGES 800000
#define IN_DIM  162
#define HID     256
#define KPAD1   192   // IN_DIM padded to multiple of 32
#define NB      ((N_NODES + 255) / 256)   // 196 scan blocks

typedef __bf16 bf16;
typedef __bf16 bf16x8 __attribute__((ext_vector_type(8)));
typedef __bf16 bf16x4 __attribute__((ext_vector_type(4)));
typedef float  f32x4  __attribute__((ext_vector_type(4)));
typedef float  f32x8  __attribute__((ext_vector_type(8)));
typedef float  f32x16 __attribute__((ext_vector_type(16)));

// ---------------------------------------------------------------------------
// Frag-major weight pack: Wf element E holds the MFMA B-frag element
//   fb = jg*2+kk, E = ((ks*16 + fb)*64 + lane)*8 + e
//   -> W[k][n], n = jg*32 + (lane&31), k = ks*32 + kk*16 + (lane>>5)*8 + e
__device__ __forceinline__ void wf_one(const float* W, bf16* Wf, int K, int E)
{
    int e    = E & 7;
    int lane = (E >> 3) & 63;
    int fb   = (E >> 9) & 15;
    int ks   = E >> 13;
    int n = (fb >> 1) * 32 + (lane & 31);
    int k = ks * 32 + (fb & 1) * 16 + (lane >> 5) * 8 + e;
    Wf[E] = (k < K) ? (bf16)W[(size_t)k * HID + n] : (bf16)0.0f;
}

// ---------------------------------------------------------------------------
// prep_all v3: one launch, partitioned by block.
//   [0, WTB)       : frag-major weight packs (4 matrices)
//   [WTB, +FPB)    : feat prep: single coalesced read, REGISTER colsum
//                    partials, LDS-staged bf16 tile, coalesced writes
//   [.., +DGB)     : degree histogram
#define WTB  ((HID * KPAD1 + 3 * HID * HID + 255) / 256)          // 960
#define FPB  ((N_NODES + 63) / 64)                                // 782
#define DGB  (N_EDGES / 256)                                      // 3125

__global__ void prep_all(const float* __restrict__ m1aw, const float* __restrict__ m1bw,
                         const float* __restrict__ m2aw, const float* __restrict__ m2bw,
                         bf16* __restrict__ Wf1, bf16* __restrict__ Wf2,
                         bf16* __restrict__ Wf3, bf16* __restrict__ Wf4,
                         const float* __restrict__ feat, bf16* __restrict__ featbf,
                         float* __restrict__ colsum8,
                         const int* __restrict__ dst, int* __restrict__ deg)
{
    __shared__ bf16  tile[64][208];   // padded rows (416B stride)
    __shared__ float pcs[4][KPAD1];   // per-rowgroup colsum partials

    const int b   = blockIdx.x;
    const int tid = threadIdx.x;

    if (b < WTB) {
        const int R1 = HID * KPAD1;
        const int R2 = HID * HID;
        int idx = b * 256 + tid;
        if (idx < R1)                 wf_one(m1aw, Wf1, IN_DIM, idx);
        else if (idx < R1 + R2)       wf_one(m1bw, Wf2, HID, idx - R1);
        else if (idx < R1 + 2 * R2)   wf_one(m2aw, Wf3, HID, idx - R1 - R2);
        else if (idx < R1 + 3 * R2)   wf_one(m2bw, Wf4, HID, idx - R1 - 2 * R2);
        return;
    }
    if (b < WTB + FPB) {
        const int fp = b - WTB;
        const int r0 = fp * 64;

        // phase A: thread t<192 owns column-quad ch=t%48 for row-group rg=t/48
        // (16 rows each). feat read ONCE, coalesced; colsum partials in regs.
        if (tid < 192) {
            const int ch = tid % 48;
            const int rg = tid / 48;
            const int c4 = ch * 4;
            float a0 = 0.0f, a1 = 0.0f, a2 = 0.0f, a3 = 0.0f;
#pragma unroll 4
            for (int k = 0; k < 16; ++k) {
                const int rl = rg * 16 + k;
                const int r  = r0 + rl;
                bf16x4 o;
                if (r < N_NODES) {
                    const float* fr = feat + (size_t)r * IN_DIM;
                    float f0 = (c4 + 0 < IN_DIM) ? fr[c4 + 0] : 0.0f;
                    float f1 = (c4 + 1 < IN_DIM) ? fr[c4 + 1] : 0.0f;
                    float f2 = (c4 + 2 < IN_DIM) ? fr[c4 + 2] : 0.0f;
                    float f3 = (c4 + 3 < IN_DIM) ? fr[c4 + 3] : 0.0f;
                    a0 += f0; a1 += f1; a2 += f2; a3 += f3;
                    o[0] = (bf16)f0; o[1] = (bf16)f1; o[2] = (bf16)f2; o[3] = (bf16)f3;
                } else {
#pragma unroll
                    for (int j = 0; j < 4; ++j) o[j] = (bf16)0.0f;
                }
                *(bf16x4*)(&tile[rl][c4]) = o;
            }
            pcs[rg][c4 + 0] = a0;
            pcs[rg][c4 + 1] = a1;
            pcs[rg][c4 + 2] = a2;
            pcs[rg][c4 + 3] = a3;
        }
        __syncthreads();

        // phase B: group-major coalesced writes: 8 groups x 64 rows x 24 cols
#pragma unroll
        for (int i = 0; i < 6; ++i) {
            int m  = i * 256 + tid;           // [0, 1536)
            int g  = m / 192;                 // 192 chunks per group
            int wg = m - g * 192;
            int eo = wg * 8;                  // elem offset in 64x24 group block
            int rl = eo / 24;
            int cc = eo - rl * 24;
            int r  = r0 + rl;
            if (r < N_NODES) {
                bf16x8 o = *(const bf16x8*)(&tile[rl][g * 24 + cc]);
                *(bf16x8*)(featbf + ((size_t)g * N_NODES + r0) * 24 + (size_t)rl * 24 + cc) = o;
            }
        }

        // phase C: combine 4 row-group partials, one global atomic per column
        if (tid < IN_DIM) {
            float s = pcs[0][tid] + pcs[1][tid] + pcs[2][tid] + pcs[3][tid];
            atomicAdd(&colsum8[(fp & 7) * KPAD1 + tid], s);
        }
        return;
    }
    {
        int e = (b - WTB - FPB) * 256 + tid;
        atomicAdd(&deg[dst[e]], 1);
    }
}

// ---------------------------------------------------------------------------
// CSR build (scan chain).
__global__ void block_degsum(const int* __restrict__ deg, int* __restrict__ bsum)
{
    __shared__ int s[256];
    int t = threadIdx.x;
    int idx = blockIdx.x * 256 + t;
    int v = (idx < N_NODES) ? deg[idx] : 0;
    s[t] = v;
    __syncthreads();
    for (int off = 128; off > 0; off >>= 1) {
        if (t < off) s[t] += s[t + off];
        __syncthreads();
    }
    if (t == 0) bsum[blockIdx.x] = s[0];
}

__global__ void scan_bsum(const int* __restrict__ bsum, int* __restrict__ gsum)
{
    __shared__ int s[256];
    int t = threadIdx.x;
    int v = (t < NB) ? bsum[t] : 0;
    s[t] = v;
    __syncthreads();
    for (int off = 1; off < 256; off <<= 1) {
        int u = (t >= off) ? s[t - off] : 0;
        __syncthreads();
        s[t] += u;
        __syncthreads();
    }
    gsum[t] = s[t] - v;
}

__global__ void block_scan_write(const int* __restrict__ deg, const int* __restrict__ gsum,
                                 int* __restrict__ rowptr, int* __restrict__ cursor)
{
    __shared__ int s[256];
    int t = threadIdx.x;
    int idx = blockIdx.x * 256 + t;
    int v = (idx < N_NODES) ? deg[idx] : 0;
    s[t] = v;
    __syncthreads();
    for (int off = 1; off < 256; off <<= 1) {
        int u = (t >= off) ? s[t - off] : 0;
        __syncthreads();
        s[t] += u;
        __syncthreads();
    }
    int excl = s[t] - v + gsum[blockIdx.x];
    if (idx < N_NODES) {
        rowptr[idx] = excl;
        cursor[idx] = excl;
    }
    if (idx == 0) rowptr[N_NODES] = N_EDGES;
}

// ---------------------------------------------------------------------------
// csr_fill v2: bucketed + XCD-pinned. Range g = blockIdx&7 owns nodes
// [g*6250, (g+1)*6250) -> a contiguous ~400KB slice of csr_src, written only
// from XCD g (round-robin dispatch). Fixes r10's 52MB partial-line writeback
// amplification (random 4B scatter dirtied 64B lines across 8 L2s).
// Each block scans a contiguous 2048-edge tile; only matching-range edges
// are filled. dst/src streams are read 8x but L3-absorbed.
#define CFT 2048
#define NRANGE ((N_NODES + 7) / 8)   // 6250

__global__ void csr_fill_b(const int* __restrict__ src, const int* __restrict__ dst,
                           int* __restrict__ cursor, int* __restrict__ csr_src)
{
    const int g    = blockIdx.x & 7;
    const int tile = blockIdx.x >> 3;
    const int lo   = g * NRANGE;
    const int hi   = lo + NRANGE;
    const int e0   = tile * CFT;
#pragma unroll
    for (int i = 0; i < CFT / 256; ++i) {
        int e = e0 + i * 256 + threadIdx.x;
        if (e < N_EDGES) {
            int d = dst[e];
            if (d >= lo && d < hi) {
                int p = atomicAdd(&cursor[d], 1);
                csr_src[p] = src[e];
            }
        }
    }
}

// ---------------------------------------------------------------------------
// Gather v5: tiled [8][N][CHUNK] input/output, XCD-pinned groups, in-register
// index list, masked unrolled row-load blocks.
template<int CHUNK, int NACT>
__launch_bounds__(256)
__global__ void gather_v5(const bf16* __restrict__ xin,
                          const int* __restrict__ rowptr,
                          const int* __restrict__ csr_src,
                          bf16* __restrict__ xout)
{
    const int g    = blockIdx.x & 7;
    const int tile = blockIdx.x >> 3;
    const int wv   = threadIdx.x >> 6;
    const int lane = threadIdx.x & 63;
    const int q    = lane >> 4;          // node within wave 0..3
    const int j    = lane & 15;          // idx slot
    const int e    = j >> 2;             // stripe 0..3
    const int c4   = j & 3;              // 16B chunk
    const int n    = tile * 16 + wv * 4 + q;
    const bool valid = (n < N_NODES);
    const bool act   = (c4 < NACT);
    const int  ce    = c4 * 8;
    const bf16* base = xin + (size_t)g * N_NODES * CHUNK;

    int r0 = 0, deg = 0;
    if (valid) {
        r0  = rowptr[n];
        deg = rowptr[n + 1] - r0;
    }

    int a0 = r0 + j;        if (a0 > N_EDGES - 1) a0 = N_EDGES - 1;
    int a1 = r0 + 16 + j;   if (a1 > N_EDGES - 1) a1 = N_EDGES - 1;
    const int i0 = csr_src[a0];
    const int i1 = csr_src[a1];

    f32x8 acc;
#pragma unroll
    for (int t = 0; t < 8; ++t) acc[t] = 0.0f;
    if (valid && e == 0 && act) {
        bf16x8 t0 = *(const bf16x8*)(base + (size_t)n * CHUNK + ce);
#pragma unroll
        for (int t = 0; t < 8; ++t) acc[t] = (float)t0[t];
    }

    const int lb = lane & ~3;

    // ---- block 1: positions 4e + k ----
    {
        const int s0 = __shfl(i0, lb + 0, 64);
        const int s1 = __shfl(i0, lb + 1, 64);
        const int s2 = __shfl(i0, lb + 2, 64);
        const int s3 = __shfl(i0, lb + 3, 64);
        const int p0 = 4 * e;
        if (act) {
            bf16x8 u0 = *(const bf16x8*)(base + (size_t)s0 * CHUNK + ce);
            bf16x8 u1 = *(const bf16x8*)(base + (size_t)s1 * CHUNK + ce);
            bf16x8 u2 = *(const bf16x8*)(base + (size_t)s2 * CHUNK + ce);
            bf16x8 u3 = *(const bf16x8*)(base + (size_t)s3 * CHUNK + ce);
            if (p0 + 0 < deg) {
#pragma unroll
                for (int t = 0; t < 8; ++t) acc[t] += (float)u0[t];
            }
            if (p0 + 1 < deg) {
#pragma unroll
                for (int t = 0; t < 8; ++t) acc[t] += (float)u1[t];
            }
            if (p0 + 2 < deg) {
#pragma unroll
                for (int t = 0; t < 8; ++t) acc[t] += (float)u2[t];
            }
            if (p0 + 3 < deg) {
#pragma unroll
                for (int t = 0; t < 8; ++t) acc[t] += (float)u3[t];
            }
        }
    }

    // ---- block 2: positions 16 + 4e + k, stripe-gated ----
    {
        const int s0 = __shfl(i1, lb + 0, 64);
        const int s1 = __shfl(i1, lb + 1, 64);
        const int s2 = __shfl(i1, lb + 2, 64);
        const int s3 = __shfl(i1, lb + 3, 64);
        const int p0 = 16 + 4 * e;
        if (act && p0 < deg) {
            bf16x8 u0 = *(const bf16x8*)(base + (size_t)s0 * CHUNK + ce);
            bf16x8 u1 = *(const bf16x8*)(base + (size_t)s1 * CHUNK + ce);
            bf16x8 u2 = *(const bf16x8*)(base + (size_t)s2 * CHUNK + ce);
            bf16x8 u3 = *(const bf16x8*)(base + (size_t)s3 * CHUNK + ce);
            {
#pragma unroll
                for (int t = 0; t < 8; ++t) acc[t] += (float)u0[t];
            }
            if (p0 + 1 < deg) {
#pragma unroll
                for (int t = 0; t < 8; ++t) acc[t] += (float)u1[t];
            }
            if (p0 + 2 < deg) {
#pragma unroll
                for (int t = 0; t < 8; ++t) acc[t] += (float)u2[t];
            }
            if (p0 + 3 < deg) {
#pragma unroll
                for (int t = 0; t < 8; ++t) acc[t] += (float)u3[t];
            }
        }
    }

    // ---- rare tail: deg > 32 ----
    for (int p = 32 + e; p < deg; p += 4) {
        const int s = csr_src[r0 + p];
        if (act) {
            bf16x8 u = *(const bf16x8*)(base + (size_t)s * CHUNK + ce);
#pragma unroll
            for (int t = 0; t < 8; ++t) acc[t] += (float)u[t];
        }
    }

#pragma unroll
    for (int t = 0; t < 8; ++t) {
        acc[t] += __shfl_xor(acc[t], 4, 64);
        acc[t] += __shfl_xor(acc[t], 8, 64);
    }

    if (valid && e == 0 && act) {
        bf16x8 o;
#pragma unroll
        for (int t = 0; t < 8; ++t) o[t] = (bf16)acc[t];
        __builtin_nontemporal_store(o,
            (bf16x8*)(xout + ((size_t)g * N_NODES + n) * CHUNK + ce));
    }
}

// ---------------------------------------------------------------------------
// Fused GIN MLP "gemm_mlp32": out = relu(relu(X@W1+b1)@W2+b2).
// 32-row blocks, 8 waves; wave w owns cols [w*32, w*32+32) over all 32 rows
// -> 32x32 per wave, acc = 1 f32x16. Grid = 1563 blocks = 12512 waves.
// B-frags coalesced from frag-major Wf (L2-resident); no K-loop barriers.
// H in LDS (16KB), (row&31)<<4 XOR swizzle.
// colsum (nullable) is 8-slotted [8][HID]; slot = blockIdx&7.
template<int KPAD, int ACHUNK, int OCHUNK>
__launch_bounds__(512)
__global__ void gemm_mlp32(const bf16* __restrict__ X,
                           const bf16* __restrict__ Wf1,
                           const float* __restrict__ bias1,
                           const bf16* __restrict__ Wf2,
                           const float* __restrict__ bias2,
                           bf16* __restrict__ out_bf,
                           float* __restrict__ colsum8,  // [8][HID] or null
                           int M)
{
    __shared__ __align__(128) bf16 sH[32 * HID];   // 16 KB

    const int tid  = threadIdx.x;
    const int w    = tid >> 6;     // col group 0..7
    const int lane = tid & 63;
    const int p    = lane >> 5;
    const int cn   = lane & 31;
    const int m_base = blockIdx.x * 32;

    int arow = m_base + cn;
    if (arow >= M) arow = M - 1;   // clamp (stores guarded)

    f32x16 acc;
#pragma unroll
    for (int r = 0; r < 16; ++r) acc[r] = 0.0f;

    // ---- phase 1: acc = X @ W1 (barrier-free) ----
    constexpr int T1 = KPAD / 16;
#pragma unroll
    for (int t = 0; t < T1; ++t) {
        bf16x8 a;
        {
            const int e = t * 16 + p * 8;
            if constexpr (ACHUNK == 0) {
                a = *(const bf16x8*)(X + (size_t)arow * KPAD + e);
            } else {
                const int gch = e / ACHUNK;
                const int off = e - gch * ACHUNK;
                a = *(const bf16x8*)(X + ((size_t)gch * N_NODES + arow) * ACHUNK + off);
            }
        }
        bf16x8 b = *(const bf16x8*)(Wf1 + ((((t >> 1) * 16 + w * 2 + (t & 1)) * 64) + lane) * 8);
        acc = __builtin_amdgcn_mfma_f32_32x32x16_bf16(a, b, acc, 0, 0, 0);
    }

    // ---- epilogue 1: H = relu(acc + b1) -> LDS, (row&31)<<4 swizzle ----
    char* sHb = (char*)sH;
    {
        const int col = w * 32 + cn;
        const float bv = bias1[col];
#pragma unroll
        for (int r = 0; r < 16; ++r) {
            const int rowl = (r & 3) + 8 * (r >> 2) + 4 * p;   // 0..31
            float v = acc[r] + bv;
            v = v > 0.0f ? v : 0.0f;
            int ba = rowl * (HID * 2) + col * 2;
            ba ^= (rowl & 31) << 4;
            *(bf16*)(sHb + ba) = (bf16)v;
        }
    }
    __syncthreads();

    // ---- phase 2: acc = H @ W2 (A from LDS, barrier-free) ----
#pragma unroll
    for (int r = 0; r < 16; ++r) acc[r] = 0.0f;

    const int hrow = cn;
    const int hswz = (hrow & 31) << 4;
    constexpr int T2 = HID / 16;
#pragma unroll
    for (int t = 0; t < T2; ++t) {
        const int kb = (t * 16 + p * 8) * 2;
        bf16x8 a = *(const bf16x8*)(sHb + ((hrow * (HID * 2) + kb) ^ hswz));
        bf16x8 b = *(const bf16x8*)(Wf2 + ((((t >> 1) * 16 + w * 2 + (t & 1)) * 64) + lane) * 8);
        acc = __builtin_amdgcn_mfma_f32_32x32x16_bf16(a, b, acc, 0, 0, 0);
    }

    // ---- epilogue 2: bias2 + relu + store + slotted colsum ----
    {
        const int col = w * 32 + cn;
        const float bv = bias2[col];
        float part = 0.0f;
#pragma unroll
        for (int r = 0; r < 16; ++r) {
            int rl = (r & 3) + 8 * (r >> 2) + 4 * p;
            int mo = m_base + rl;
            if (mo < M) {
                float v = acc[r] + bv;
                v = v > 0.0f ? v : 0.0f;
                if constexpr (OCHUNK == 0)
                    out_bf[(size_t)mo * HID + col] = (bf16)v;
                else
                    out_bf[((size_t)w * N_NODES + mo) * OCHUNK + cn] = (bf16)v;
                part += v;
            }
        }
        if (colsum8) {
            part += __shfl_xor(part, 32, 64);   // combine the two p-halves
            if (p == 0) atomicAdd(&colsum8[(blockIdx.x & 7) * HID + col], part);
        }
    }
}

// ---------------------------------------------------------------------------
// Graph head: three GEMVs + sum + final GEMV, single block of 256 threads.
// All colsums are 8-slotted.
__global__ void graph_head(const float* __restrict__ cs0_8,
                           const float* __restrict__ cs1_8,
                           const float* __restrict__ cs2_8,
                           const float* __restrict__ g0w, const float* __restrict__ g0b,
                           const float* __restrict__ g1w, const float* __restrict__ g1b,
                           const float* __restrict__ g2w, const float* __restrict__ g2b,
                           const float* __restrict__ glw, const float* __restrict__ glb,
                           float* __restrict__ gvec)
{
    __shared__ float v0[IN_DIM], v1[HID], v2[HID], gs[HID];
    int t = threadIdx.x;
    if (t < IN_DIM) {
        float s = 0.0f;
#pragma unroll
        for (int i = 0; i < 8; ++i) s += cs0_8[i * KPAD1 + t];
        v0[t] = s;
    }
    {
        float s1 = 0.0f, s2 = 0.0f;
#pragma unroll
        for (int i = 0; i < 8; ++i) {
            s1 += cs1_8[i * HID + t];
            s2 += cs2_8[i * HID + t];
        }
        v1[t] = s1;
        v2[t] = s2;
    }
    __syncthreads();

    float a0 = 0.0f, a1 = 0.0f, a2 = 0.0f;
    for (int k = 0; k < IN_DIM; ++k) a0 += v0[k] * g0w[k * HID + t];
    for (int k = 0; k < HID; ++k) {
        a1 += v1[k] * g1w[k * HID + t];
        a2 += v2[k] * g2w[k * HID + t];
    }
    float e0 = fmaxf(a0 + g0b[t], 0.0f);
    float e1 = fmaxf(a1 + g1b[t], 0.0f);
    float e2 = fmaxf(a2 + g2b[t], 0.0f);
    gs[t] = e0 + e1 + e2;
    __syncthreads();

    float a3 = 0.0f;
    for (int k = 0; k < HID; ++k) a3 += gs[k] * glw[k * HID + t];
    gvec[t] = fmaxf(a3 + glb[t], 0.0f);
}

// ---------------------------------------------------------------------------
// out[n,c] = node2[n,c](bf16) + gvec[c] (f32 out); 4 elements per thread.
__global__ void final_add(const bf16* __restrict__ node2,
                          const float* __restrict__ gvec,
                          float* __restrict__ out)
{
    int idx = blockIdx.x * blockDim.x + threadIdx.x;
    size_t base = (size_t)idx * 4;
    int c = (int)(base & (HID - 1));
    bf16x4 v = *(const bf16x4*)(node2 + base);
    f32x4 g = *(const f32x4*)(gvec + c);
    f32x4 o;
#pragma unroll
    for (int j = 0; j < 4; ++j) o[j] = (float)v[j] + g[j];
    *(f32x4*)(out + base) = o;
}

// ---------------------------------------------------------------------------
extern "C" void kernel_launch(void* const* d_in, const int* in_sizes, int n_in,
                              void* d_out, int out_size, void* d_ws, size_t ws_size,
                              hipStream_t stream)
{
    const float* feat = (const float*)d_in[0];
    const int*   ei   = (const int*)d_in[1];
    const int*   src  = ei;
    const int*   dst  = ei + N_EDGES;
    const float* g0w = (const float*)d_in[2],  *g0b = (const float*)d_in[3];
    const float* g1w = (const float*)d_in[4],  *g1b = (const float*)d_in[5];
    const float* g2w = (const float*)d_in[6],  *g2b = (const float*)d_in[7];
    const float* glw = (const float*)d_in[8],  *glb = (const float*)d_in[9];
    const float* m1aw = (const float*)d_in[10], *m1ab = (const float*)d_in[11];
    const float* m1bw = (const float*)d_in[12], *m1bb = (const float*)d_in[13];
    const float* m2aw = (const float*)d_in[14], *m2ab = (const float*)d_in[15];
    const float* m2bw = (const float*)d_in[16], *m2bb = (const float*)d_in[17];
    float* out = (float*)d_out;

    char* ws = (char*)d_ws;
    size_t off = 0;
    auto alloc = [&](size_t bytes) -> void* {
        void* p = ws + off;
        off += (bytes + 255) & ~(size_t)255;
        return p;
    };
    bf16*  featbf = (bf16*)alloc((size_t)N_NODES * KPAD1 * 2);   // tiled [8][N][24]
    bf16*  xsum  = (bf16*) alloc((size_t)N_NODES * KPAD1 * 2);   // tiled [8][N][24]
    bf16*  y2    = (bf16*) alloc((size_t)N_NODES * HID * 2);     // tiled [8][N][32]
    bf16*  node2 = (bf16*) alloc((size_t)N_NODES * HID * 2);     // linear
    bf16*  node1 = (bf16*) alloc((size_t)N_NODES * HID * 2);     // tiled [8][N][32]
    bf16*  Wf1   = (bf16*) alloc((size_t)HID * KPAD1 * 2);       // frag-major
    bf16*  Wf2   = (bf16*) alloc((size_t)HID * HID * 2);
    bf16*  Wf3   = (bf16*) alloc((size_t)HID * HID * 2);
    bf16*  Wf4   = (bf16*) alloc((size_t)HID * HID * 2);
    int*   deg     = (int*)alloc((size_t)N_NODES * 4);
    int*   rowptr  = (int*)alloc((size_t)(N_NODES + 1) * 4);
    int*   cursor  = (int*)alloc((size_t)N_NODES * 4);
    int*   csr_src = (int*)alloc((size_t)N_EDGES * 4);
    int*   bsum    = (int*)alloc(256 * 4);
    int*   gsum    = (int*)alloc(256 * 4);
    float* csums   = (float*)alloc((8 * KPAD1 + 8 * HID + 8 * HID + HID) * 4);
    float* colsum0_8 = csums;                          // 8 x 192 slots
    float* colsum1_8 = csums + 8 * KPAD1;              // 8 x 256 slots
    float* colsum2_8 = csums + 8 * KPAD1 + 8 * HID;    // 8 x 256 slots
    float* gvec      = csums + 8 * KPAD1 + 16 * HID;   // 256

    hipMemsetAsync(csums, 0, (8 * KPAD1 + 16 * HID) * 4, stream);
    hipMemsetAsync(deg, 0, (size_t)N_NODES * 4, stream);

    // all independent preprocessing in one launch
    prep_all<<<WTB + FPB + DGB, 256, 0, stream>>>(
        m1aw, m1bw, m2aw, m2bw, Wf1, Wf2, Wf3, Wf4,
        feat, featbf, colsum0_8, dst, deg);

    // CSR scan chain
    block_degsum<<<NB, 256, 0, stream>>>(deg, bsum);
    scan_bsum<<<1, 256, 0, stream>>>(bsum, gsum);
    block_scan_write<<<NB, 256, 0, stream>>>(deg, gsum, rowptr, cursor);
    // bucketed, XCD-pinned fill (write-amplification fix)
    csr_fill_b<<<((N_EDGES + CFT - 1) / CFT) * 8, 256, 0, stream>>>(src, dst, cursor, csr_src);

    const int gtiles = (N_NODES + 15) / 16;   // 4 nodes/wave x 4 waves
    // xsum = bf16(feat + gather(feat)) — tiled, XCD-pinned, register-idx
    gather_v5<24, 3><<<gtiles * 8, 256, 0, stream>>>(featbf, rowptr, csr_src, xsum);

    const int gblocks = (N_NODES + 31) / 32;   // 1563
    // node1 = relu(relu(xsum@W1+b1)@W2+b2), colsum1 fused   (A tiled24 -> tiled32 out)
    gemm_mlp32<KPAD1, 24, 32><<<gblocks, 512, 0, stream>>>(
        xsum, Wf1, m1ab, Wf2, m1bb, node1, colsum1_8, N_NODES);
    // y2 = bf16(node1 + gather(node1)) — tiled, XCD-pinned, register-idx
    gather_v5<32, 4><<<gtiles * 8, 256, 0, stream>>>(node1, rowptr, csr_src, y2);
    // node2 = relu(relu(y2@W3+b3)@W4+b4), colsum2 fused     (A tiled32 -> linear out)
    gemm_mlp32<HID, 32, 0><<<gblocks, 512, 0, stream>>>(
        y2, Wf3, m2ab, Wf4, m2bb, node2, colsum2_8, N_NODES);
    // graph head -> gvec = g_last
    graph_head<<<1, 256, 0, stream>>>(colsum0_8, colsum1_8, colsum2_8,
                                      g0w, g0b, g1w, g1b, g2w, g2b, glw, glb, gvec);
    // out = node2 + gvec
    final_add<<<((size_t)N_NODES * HID / 4 + 255) / 256, 256, 0, stream>>>(node2, gvec, out);
    (void)in_sizes; (void)n_in; (void)out_size; (void)ws_size;
}